// Round 13
// baseline (271.139 us; speedup 1.0000x reference)
//
#include <hip/hip_runtime.h>
#include <hip/hip_bf16.h>

// Problem constants (WholeBrainRateModel)
constexpr int kN   = 50000;    // nodes
constexpr int kH   = 64;       // hidden
constexpr int kB   = 2;        // batch
constexpr int kE   = 1000000;  // edges
constexpr int kObs = 128;
constexpr int kA   = 18;
constexpr int kAff = 512;
constexpr int kEff = 256;
constexpr int kNH  = kN * kH;
constexpr int kOutOff = 2 * kB * kA;  // 72 elements: mean+log_std before next_state
constexpr int kRanges = 8;                // node ranges (bid&7 -> XCD heuristic)
constexpr int kNr  = kN / kRanges;        // 6250 nodes per range (25 KB LDS)
constexpr int kChunks = 64;               // edge chunks
constexpr int kEc  = kE / kChunks;        // 15625 edges per chunk
constexpr int kHistB = kRanges * kChunks; // 512 hist/scatter blocks (1024 thr)
constexpr int kPackPerR = (kNr + 127) / 128;      // 49 pack blocks per range
constexpr int kPackBlocks = kRanges * kPackPerR;  // 392 (range-aligned)
constexpr int kWprepBlocks = 20;                  // 20480 / 1024
constexpr int kScanB = (kN + 255) / 256;          // 196 (1 node/thread)
constexpr int kGatB = kRanges * 1563;             // 12504 (range-aligned gather)
constexpr int kUpdPerR = (kNr + 7) / 8;           // 782 update waves per range
constexpr int kUpdB = kRanges * kUpdPerR;         // 6256 (1-wave blocks)

typedef __attribute__((ext_vector_type(8))) short short8_t;  // 8 bf16 (4 VGPRs)
typedef __attribute__((ext_vector_type(4))) float f32x4_t;

// dtype-adaptive load/store (flag==1 -> float32 buffers, else bf16).
__device__ __forceinline__ float ldf(const void* p, int i, int f32) {
  if (f32) return ((const float*)p)[i];
  unsigned short u = ((const unsigned short*)p)[i];
  union { unsigned int x; float f; } v; v.x = ((unsigned int)u) << 16; return v.f;
}
__device__ __forceinline__ void stf(void* p, int i, float val, int f32) {
  if (f32) ((float*)p)[i] = val;
  else ((__hip_bfloat16*)p)[i] = __float2bfloat16(val);
}
__device__ __forceinline__ float lo16(unsigned int w) {
  union { unsigned int i; float f; } v; v.i = w << 16; return v.f;
}
__device__ __forceinline__ float hi16(unsigned int w) {
  union { unsigned int i; float f; } v; v.i = w & 0xffff0000u; return v.f;
}
__device__ __forceinline__ float b2f(unsigned short u) {
  union { unsigned int i; float f; } v; v.i = ((unsigned int)u) << 16; return v.f;
}
__device__ __forceinline__ unsigned int f2b(float f) {  // rne bf16 bits
  union { float f; unsigned int u; } v; v.f = f;
  unsigned int r = v.u + 0x7fffu + ((v.u >> 16) & 1u);
  return r >> 16;
}
// fast transcendentals: v_exp_f32 + v_rcp_f32; error ~1e-6 rel, far below the
// bf16 rounding already present in the pipeline (absmax budget ~2e-3).
__device__ __forceinline__ float fsig(float x) {
  return __builtin_amdgcn_rcpf(1.f + __expf(-x));
}
__device__ __forceinline__ float ftanh(float x) {
  return 1.f - 2.f * __builtin_amdgcn_rcpf(__expf(2.f * x) + 1.f);
}
// wave-0 dtype detector (identical data in every block -> identical answer)
__device__ __forceinline__ int detect64(const unsigned short* wprobe, int t) {
  int hits = 0;
  for (int k = 0; k < 4; ++k) {
    unsigned short u = wprobe[(t * 4 + k) * 2];
    int e = (u >> 7) & 0xFF;
    if ((u & 0x7FFFu) != 0 && e >= 108 && e <= 128) hits++;
  }
  for (int off = 32; off; off >>= 1) hits += __shfl_down(hits, off);
  return (hits < 128) ? 1 : 0;  // few plausible-bf16 => f32
}

// --- fused prep (1024 thr): b0 = detect+flags+proj; b1..512 = hist; wprep ---
// Histogram with ZERO global atomics (rounds 3/4: every global atomic costs a
// ~32 B EA write packet; 1M of them = ~32 MB + 45+ us). Round 5 lesson: keep
// >=2 blk/CU and short per-thread loops. Block (r,c) LDS-counts chunk c's
// edges landing in range r, then plain coalesced stores to deg_c[c][range r].
extern "C" __global__ __launch_bounds__(1024) void k_prep(
    const unsigned short* __restrict__ wprobe,
    const void* __restrict__ obs,
    const void* __restrict__ W_in,
    const void* __restrict__ b_in,
    const int* __restrict__ aff_idx,
    const int* __restrict__ dst,
    const void* __restrict__ W_msg,
    const void* __restrict__ W_gate,
    const void* __restrict__ W_cand,
    int* __restrict__ dflag,
    int* __restrict__ flags,
    float* __restrict__ projected,
    int* __restrict__ deg_c,
    unsigned short* __restrict__ wt,
    float* __restrict__ eff_acc) {
  __shared__ int sdeg[kNr];
  int t = threadIdx.x, b = blockIdx.x;
  if (b == 0) {
    __shared__ int sflag;
    if (t < 64) { int f = detect64(wprobe, t); if (t == 0) { sflag = f; dflag[0] = f; } }
    for (int i = t; i < kN; i += 1024) flags[i] = 0;
    eff_acc[t] = 0.f;                      // 8 range slices x 128
    __syncthreads();
    int f32 = sflag;
    if (t < kAff) flags[aff_idx[t]] = 1;
    if (t < kB * kH) {
      int bb = t >> 6, h = t & 63;
      float acc = ldf(b_in, h, f32);
      for (int o = 0; o < kObs; ++o)
        acc += ldf(obs, bb * kObs + o, f32) * ldf(W_in, o * kH + h, f32);
      projected[t] = acc;
    }
  } else if (b <= kHistB) {
    int h = b - 1, r = h & 7, c = h >> 3;
    int r0 = r * kNr;
    for (int i = t; i < kNr; i += 1024) sdeg[i] = 0;
    __syncthreads();
    int end = (c + 1) * kEc;
    for (int e = c * kEc + t; e < end; e += 1024) {
      unsigned rel = (unsigned)(dst[e] - r0);
      if (rel < (unsigned)kNr) atomicAdd(&sdeg[rel], 1);  // LDS atomic only
    }
    __syncthreads();
    for (int i = t; i < kNr; i += 1024) deg_c[c * kN + r0 + i] = sdeg[i];
  } else {
    __shared__ int sflag;
    if (t < 64) { int f = detect64(wprobe, t); if (t == 0) sflag = f; }
    __syncthreads();
    int f32 = sflag;
    int i = (b - 1 - kHistB) * 1024 + t;  // 0..20479
    if (i < 4096) {
      int n = i >> 6, k = i & 63;
      wt[i] = (unsigned short)f2b(ldf(W_msg, k * 64 + n, f32));
    } else if (i < 12288) {
      int j = i - 4096; int n = j >> 7, k = j & 127;
      wt[i] = (unsigned short)f2b(ldf(W_gate, k * 64 + n, f32));
    } else if (i < 20480) {
      int j = i - 12288; int n = j >> 7, k = j & 127;
      wt[i] = (unsigned short)f2b(ldf(W_cand, k * 64 + n, f32));
    }
  }
}

// --- scan: 196 blocks x 256 thr, 1 node/thread ------------------------------
extern "C" __global__ void k_scan1(const int* __restrict__ deg_c,
                                   int* __restrict__ row_off,
                                   int* __restrict__ partials) {
  __shared__ int sd[256];
  int t = threadIdx.x;
  int n = blockIdx.x * 256 + t;
  int s = 0;
  if (n < kN) {
    for (int c = 0; c < kChunks; ++c) s += deg_c[c * kN + n];
  }
  sd[t] = s;
  __syncthreads();
  for (int off = 1; off < 256; off <<= 1) {
    int v = (t >= off) ? sd[t - off] : 0;
    __syncthreads();
    sd[t] += v;
    __syncthreads();
  }
  int excl = sd[t] - s;
  if (t == 255) partials[blockIdx.x] = sd[255];
  if (n < kN) row_off[n] = excl;
}

// scan2 folded in; additionally transforms deg_c in place into
// chunk_base[c][n] = row_off[n] + sum_{c'<c} deg_c[c'][n]  (atomic-free
// scatter positions). Each node column is owned by exactly one thread.
extern "C" __global__ void k_scan3(int* __restrict__ row_off,
                                   const int* __restrict__ partials,
                                   int* __restrict__ deg_c) {
  __shared__ int sd[256];
  int t = threadIdx.x;
  int s = 0;
  for (int j = t; j < (int)blockIdx.x; j += 256) s += partials[j];
  sd[t] = s;
  __syncthreads();
  for (int off = 128; off; off >>= 1) {
    if (t < off) sd[t] += sd[t + off];
    __syncthreads();
  }
  int base = sd[0];
  int n = blockIdx.x * 256 + t;
  if (n < kN) {
    int v = row_off[n] + base;
    row_off[n] = v;
    int run = v;
#pragma unroll 8
    for (int c = 0; c < kChunks; ++c) {
      int d = deg_c[c * kN + n];
      deg_c[c * kN + n] = run;   // in-place: deg -> chunk_base
      run += d;
    }
  }
  if (blockIdx.x == 0 && t == 0) row_off[kN] = kE;
}

// --- scatter (+pack riding along), 1024 thr: ZERO global atomics ------------
// Block (r,c): load range r's chunk_base slice into an LDS cursor, then for
// chunk c's in-range edges take slots via LDS atomicAdd and store. Slots are
// disjoint across chunks by construction (chunk_base prefix). bid&7 = r keeps
// each range's ~500 KB sorted_src window written by one XCD (L2 locality).
// Pack blocks (bid >= 512): range-aligned: pack block p handles nodes of
// range p&7 -> pk's range-r lines are written by XCD r's L2.
extern "C" __global__ __launch_bounds__(1024) void k_scatter(
    const int* __restrict__ src,
    const int* __restrict__ dst,
    const int* __restrict__ chunk_base,
    int* __restrict__ sorted_src,
    const unsigned short* __restrict__ wprobe,
    const void* __restrict__ state,
    unsigned int* __restrict__ pack) {
  __shared__ int scur[kNr];
  int t = threadIdx.x;
  if (blockIdx.x < kHistB) {
    int r = blockIdx.x & 7, c = blockIdx.x >> 3;
    int r0 = r * kNr;
    for (int i = t; i < kNr; i += 1024) scur[i] = chunk_base[c * kN + r0 + i];
    __syncthreads();
    int end = (c + 1) * kEc;
    for (int e = c * kEc + t; e < end; e += 1024) {
      unsigned rel = (unsigned)(dst[e] - r0);
      if (rel < (unsigned)kNr) {
        int pos = atomicAdd(&scur[rel], 1);   // LDS atomic only
        sorted_src[pos] = src[e];
      }
    }
  } else {
    __shared__ int sflag;
    if (t < 64) { int f = detect64(wprobe, t); if (t == 0) sflag = f; }
    __syncthreads();
    int f32 = sflag;
    int p = blockIdx.x - kHistB;           // kHistB = 512 (div by 8): XCD = p&7
    int x = p & 7, j = p >> 3;
    int nb = x * kNr + j * 128;            // first node of this pack block
    int nl = min(nb + 128, (x + 1) * kNr); // range-local node limit
    int i = nb * 64 + t * 8;               // 8 elems/thread
    if (i < nl * 64) {
      uint4 o0, o1;
      if (!f32) {
        // bf16 inputs: pack is a pure bit-interleave (no rounding round-trip)
        uint4 a = *(const uint4*)((const unsigned short*)state + i);
        uint4 c4 = *(const uint4*)((const unsigned short*)state + kNH + i);
        o0.x = (a.x & 0xffffu) | (c4.x << 16);
        o0.y = (a.x >> 16)     | (c4.x & 0xffff0000u);
        o0.z = (a.y & 0xffffu) | (c4.y << 16);
        o0.w = (a.y >> 16)     | (c4.y & 0xffff0000u);
        o1.x = (a.z & 0xffffu) | (c4.z << 16);
        o1.y = (a.z >> 16)     | (c4.z & 0xffff0000u);
        o1.z = (a.w & 0xffffu) | (c4.w << 16);
        o1.w = (a.w >> 16)     | (c4.w & 0xffff0000u);
      } else {
        const float* sf = (const float*)state;
        unsigned int w[8];
#pragma unroll
        for (int k = 0; k < 8; ++k)
          w[k] = f2b(sf[i + k]) | (f2b(sf[kNH + i + k]) << 16);
        o0 = make_uint4(w[0], w[1], w[2], w[3]);
        o1 = make_uint4(w[4], w[5], w[6], w[7]);
      }
      *(uint4*)&pack[i] = o0;
      *(uint4*)&pack[i + 4] = o1;
    }
  }
}

// --- gather: one wave per node over its contiguous edge span ----------------
// XCD-range-aligned grid: bid&7 = node range r, so this block runs on the
// SAME XCD (bid%8 heuristic) whose L2 wrote range r's sorted_src in
// k_scatter -> span reads hit dirty-local lines instead of migrating them.
// 16-lane groups: group g handles edge e+g (and e+4+g), lane loads uint4
// (16 B = 4 packed h-columns). Cross-group shfl_xor(16/32) reduce at the end.
extern "C" __global__ __launch_bounds__(256) void k_gather(
    const unsigned int* __restrict__ pack,
    const int* __restrict__ row_off,     // span = [off[n], off[n+1])
    const int* __restrict__ sorted_src,
    unsigned int* __restrict__ agg) {
  int wave = threadIdx.x >> 6, lane = threadIdx.x & 63;
  int x = blockIdx.x & 7, j = blockIdx.x >> 3;
  int local = j * 4 + wave;
  if (local >= kNr) return;
  int n = x * kNr + local;
  int s  = row_off[n];
  int en = row_off[n + 1];
  int g = lane >> 4, col = lane & 15;
  const uint4* pk4 = (const uint4*)pack;
  float a0x = 0.f, a0y = 0.f, a0z = 0.f, a0w = 0.f;
  float a1x = 0.f, a1y = 0.f, a1z = 0.f, a1w = 0.f;
  for (int e = s; e < en; e += 8) {
#pragma unroll
    for (int h = 0; h < 2; ++h) {
      int ee = e + h * 4 + g;
      int idx = sorted_src[min(ee, en - 1)];
      uint4 wv = pk4[idx * 16 + col];
      if (ee >= en) { wv.x = 0u; wv.y = 0u; wv.z = 0u; wv.w = 0u; }
      a0x += lo16(wv.x); a1x += hi16(wv.x);
      a0y += lo16(wv.y); a1y += hi16(wv.y);
      a0z += lo16(wv.z); a1z += hi16(wv.z);
      a0w += lo16(wv.w); a1w += hi16(wv.w);
    }
  }
  // reduce the 4 edge-groups (lanes differing in bits 4,5) onto group 0
  a0x += __shfl_xor(a0x, 16); a0x += __shfl_xor(a0x, 32);
  a0y += __shfl_xor(a0y, 16); a0y += __shfl_xor(a0y, 32);
  a0z += __shfl_xor(a0z, 16); a0z += __shfl_xor(a0z, 32);
  a0w += __shfl_xor(a0w, 16); a0w += __shfl_xor(a0w, 32);
  a1x += __shfl_xor(a1x, 16); a1x += __shfl_xor(a1x, 32);
  a1y += __shfl_xor(a1y, 16); a1y += __shfl_xor(a1y, 32);
  a1z += __shfl_xor(a1z, 16); a1z += __shfl_xor(a1z, 32);
  a1w += __shfl_xor(a1w, 16); a1w += __shfl_xor(a1w, 32);
  if (g == 0) {
    uint4 o;
    o.x = f2b(a0x) | (f2b(a1x) << 16);
    o.y = f2b(a0y) | (f2b(a1y) << 16);
    o.z = f2b(a0z) | (f2b(a1z) << 16);
    o.w = f2b(a0w) | (f2b(a1w) << 16);
    ((uint4*)agg)[n * 16 + col] = o;
  }
}

// --- update (MFMA), fully WAVE-AUTONOMOUS (round 13) ------------------------
// Round-12 lesson: 44 us invariant across occupancy/weight-location/XCD
// variants with all engines <13% busy => per-wave latency serialized by the
// 4-wave block's barriers. Now: 1 wave = 1 block = 8 nodes; staging, MFMA,
// epilogue, copy-out (own 2x2KB contiguous slab), eff-scan are ALL
// wave-private; __syncthreads is a single-wave no-op; ~24 blocks/CU resident.
// Eff rows: register pre-sum per lane column, then 2 atomics/lane into the
// PER-RANGE slice eff_acc[range][128] (contention /8; no fence — kernel
// boundary is the one cross-XCD flush, round-10 lesson).
extern "C" __global__ __launch_bounds__(64, 6) void k_update(
    const unsigned int* __restrict__ pk,
    const unsigned short* __restrict__ wt,   // prepped bf16 Wt msg|gate|cand
    const void* __restrict__ b_gate,
    const void* __restrict__ b_cand,
    const unsigned int* __restrict__ agg,
    const int* __restrict__ flags,
    const float* __restrict__ projected,
    const int* __restrict__ dflag,
    void* __restrict__ out,
    const int* __restrict__ eff_idx,
    float* __restrict__ eff_acc) {
  __shared__ uint4 lx4[274];     // 4384 B: strip [16 rows][136 u16] (+pad)
  __shared__ int smatch[256];
  __shared__ int smcnt;
  unsigned short* lx = (unsigned short*)lx4;
  int f32 = dflag[0];
  int lane = threadIdx.x;        // 64 threads = 1 wave
  int q = lane >> 4, l15 = lane & 15;
  int x = blockIdx.x & 7, jb = blockIdx.x >> 3;
  int ndw = x * kNr + jb * 8;    // wave's first node
  int rend = (x + 1) * kNr;      // range-local node limit
  if (ndw >= rend) return;
  if (lane == 0) smcnt = 0;

  const uint4* pk4 = (const uint4*)pk;
  const uint4* ag4 = (const uint4*)agg;
  // staging: state -> cols 0-63, agg -> cols 64-127 (own 8 nodes, 2 iters)
  for (int j = lane; j < 128; j += 64) {
    int ndl = j >> 4, c4 = j & 15;
    int ndg = min(ndw + ndl, rend - 1);
    uint4 pv = pk4[ndg * 16 + c4];
    uint4 av = ag4[ndg * 16 + c4];
    int r0 = 2 * ndl;
    *(uint2*)&lx[r0 * 136 + c4 * 4] =
        make_uint2((pv.x & 0xffffu) | (pv.y << 16), (pv.z & 0xffffu) | (pv.w << 16));
    *(uint2*)&lx[(r0 + 1) * 136 + c4 * 4] =
        make_uint2((pv.x >> 16) | (pv.y & 0xffff0000u), (pv.z >> 16) | (pv.w & 0xffff0000u));
    *(uint2*)&lx[r0 * 136 + 64 + c4 * 4] =
        make_uint2((av.x & 0xffffu) | (av.y << 16), (av.z & 0xffffu) | (av.w << 16));
    *(uint2*)&lx[(r0 + 1) * 136 + 64 + c4 * 4] =
        make_uint2((av.x >> 16) | (av.y & 0xffff0000u), (av.z >> 16) | (av.w & 0xffff0000u));
  }
  __syncthreads();   // single-wave: compiles to lgkmcnt wait only

  const unsigned short* wm = wt;            // msg^T  [64][64]  (row = out col)
  const unsigned short* wg = wt + 4096;     // gate^T [64][128]
  const unsigned short* wc = wt + 12288;    // cand^T [64][128]

  // --- msg phase: C[16x64] = agg[16x64] @ W_msg[64x64] ---
  short8_t a0 = *(const short8_t*)&lx[l15 * 136 + 64 + q * 8];
  short8_t a1 = *(const short8_t*)&lx[l15 * 136 + 96 + q * 8];
  f32x4_t msgc[4];
#pragma unroll
  for (int ct = 0; ct < 4; ++ct) {
    f32x4_t acc = {0.f, 0.f, 0.f, 0.f};
    short8_t b0 = *(const short8_t*)&wm[(ct * 16 + l15) * 64 + q * 8];
    short8_t b1 = *(const short8_t*)&wm[(ct * 16 + l15) * 64 + 32 + q * 8];
    acc = __builtin_amdgcn_mfma_f32_16x16x32_bf16(a0, b0, acc, 0, 0, 0);
    acc = __builtin_amdgcn_mfma_f32_16x16x32_bf16(a1, b1, acc, 0, 0, 0);
    msgc[ct] = acc;
  }
  // combined = msg + inject -> back into cols 64-127
  int nA = ndw + q * 2, nB = nA + 1;
  int flA = (nA < rend) ? flags[nA] : 0;
  int flB = (nB < rend) ? flags[nB] : 0;
#pragma unroll
  for (int ct = 0; ct < 4; ++ct) {
    int col = ct * 16 + l15;
    float pj0 = projected[col], pj1 = projected[64 + col];
#pragma unroll
    for (int r = 0; r < 4; ++r) {
      int row = q * 4 + r;
      int fl = (r < 2) ? flA : flB;
      float inj = fl ? ((row & 1) ? pj1 : pj0) : 0.f;
      lx[row * 136 + 64 + col] = (unsigned short)f2b(msgc[ct][r] + inj);
    }
  }

  // --- gate/cand phase: K=128 over [state | combined] ---
  short8_t xa[4];
#pragma unroll
  for (int ks = 0; ks < 4; ++ks)
    xa[ks] = *(const short8_t*)&lx[l15 * 136 + ks * 32 + q * 8];
  // prev-state (own rows) to regs BEFORE result staging overwrites the strip
  float ps[16];
#pragma unroll
  for (int ct = 0; ct < 4; ++ct)
#pragma unroll
    for (int rp = 0; rp < 2; ++rp) {
      int row = q * 4 + 2 * rp;
      ps[ct * 4 + rp * 2 + 0] = b2f(lx[row * 136 + ct * 16 + l15]);
      ps[ct * 4 + rp * 2 + 1] = b2f(lx[(row + 1) * 136 + ct * 16 + l15]);
    }
  // result staging: strip reused as [16 rows][64] f32 (4096 B; row = nl*2+p)
  float* soutw = (float*)lx4;
#pragma unroll
  for (int ct = 0; ct < 4; ++ct) {
    f32x4_t accg = {0.f, 0.f, 0.f, 0.f}, accc = {0.f, 0.f, 0.f, 0.f};
#pragma unroll
    for (int ks = 0; ks < 4; ++ks) {
      short8_t bg = *(const short8_t*)&wg[(ct * 16 + l15) * 128 + ks * 32 + q * 8];
      short8_t bc = *(const short8_t*)&wc[(ct * 16 + l15) * 128 + ks * 32 + q * 8];
      accg = __builtin_amdgcn_mfma_f32_16x16x32_bf16(xa[ks], bg, accg, 0, 0, 0);
      accc = __builtin_amdgcn_mfma_f32_16x16x32_bf16(xa[ks], bc, accc, 0, 0, 0);
    }
    int col = ct * 16 + l15;
    float bgv = ldf(b_gate, col, f32), bcv = ldf(b_cand, col, f32);
#pragma unroll
    for (int rp = 0; rp < 2; ++rp) {
      int r = q * 4 + 2 * rp;   // strip row (batch0); r+1 = batch1
      float z0 = fsig(accg[2 * rp] + bgv);
      float c0 = ftanh(accc[2 * rp] + bcv);
      soutw[r * 64 + col] = (1.f - z0) * ps[ct * 4 + rp * 2 + 0] + z0 * c0;
      float z1 = fsig(accg[2 * rp + 1] + bgv);
      float c1 = ftanh(accc[2 * rp + 1] + bcv);
      soutw[(r + 1) * 64 + col] = (1.f - z1) * ps[ct * 4 + rp * 2 + 1] + z1 * c1;
    }
  }
  __syncthreads();

  int nlim = min(8, rend - ndw);
  // eff-membership scan: 4 entries/lane (L2-hot)
  for (int i = lane; i < kEff; i += 64) {
    unsigned rel = (unsigned)(eff_idx[i] - ndw);
    if (rel < (unsigned)nlim) { int s = atomicAdd(&smcnt, 1); smatch[s] = (int)rel; }
  }
  __syncthreads();

  // wave-contiguous aligned copy-out (2 KB/plane; 16B-aligned bases)
  int nvalid = nlim * 64;
  if (f32) {
    float* po = (float*)out + kOutOff;
#pragma unroll
    for (int p = 0; p < 2; ++p)
      for (int j = lane * 4; j < nvalid; j += 256) {
        int ndl = j >> 6, c = j & 63;
        float4 v = *(float4*)((char*)lx4 + ((ndl * 2 + p) * 64 + c) * 4);
        *(float4*)(po + p * kNH + ndw * 64 + j) = v;
      }
  } else {
    unsigned short* po = (unsigned short*)out + kOutOff;
#pragma unroll
    for (int p = 0; p < 2; ++p)
      for (int j = lane * 8; j < nvalid; j += 512) {
        int ndl = j >> 6, c = j & 63;
        const char* base = (const char*)lx4 + ((ndl * 2 + p) * 64 + c) * 4;
        float4 v0 = *(const float4*)base;
        float4 v1 = *(const float4*)(base + 16);
        uint4 o;
        o.x = f2b(v0.x) | (f2b(v0.y) << 16);
        o.y = f2b(v0.z) | (f2b(v0.w) << 16);
        o.z = f2b(v1.x) | (f2b(v1.y) << 16);
        o.w = f2b(v1.z) | (f2b(v1.w) << 16);
        *(uint4*)(po + p * kNH + ndw * 64 + j) = o;
      }
  }

  // eff accumulation: register pre-sum, then 2 atomics/lane to range slice
  int cnt = smcnt;
  if (cnt) {
    float a0s = 0.f, a1s = 0.f;
    const float* sf = (const float*)lx4;
    for (int m = 0; m < cnt; ++m) {
      int rel = smatch[m];
      float v0 = sf[(rel * 2 + 0) * 64 + lane];
      float v1 = sf[(rel * 2 + 1) * 64 + lane];
      if (!f32) { v0 = b2f((unsigned short)f2b(v0)); v1 = b2f((unsigned short)f2b(v1)); }
      a0s += v0; a1s += v1;
    }
    atomicAdd(&eff_acc[x * 128 + lane], a0s);        // device-scope, no fence
    atomicAdd(&eff_acc[x * 128 + 64 + lane], a1s);
  }
}

// --- readout: tiny decode + policy heads from per-range eff_acc slices ------
// Kernel boundary provides cross-XCD visibility of k_update's eff_acc atomics
// (one command-processor flush instead of per-block fences — round 10).
extern "C" __global__ void k_readout(const void* __restrict__ W_dec,
                                     const void* __restrict__ b_dec,
                                     const void* __restrict__ W_mean,
                                     const void* __restrict__ b_mean,
                                     const void* __restrict__ W_ls,
                                     const void* __restrict__ b_ls,
                                     const float* __restrict__ eff_acc,
                                     const int* __restrict__ dflag,
                                     void* __restrict__ out) {
  __shared__ float ro[128], dec[128];
  int f32 = dflag[0];
  int t = threadIdx.x;            // 128 threads
  if (t < 128) {
    float s = 0.f;
#pragma unroll
    for (int r = 0; r < kRanges; ++r) s += eff_acc[r * 128 + t];
    ro[t] = s * (1.f / kEff);
  }
  __syncthreads();
  if (t < 128) {
    int bb = t >> 6, h = t & 63;
    float d = ldf(b_dec, h, f32);
    for (int k = 0; k < 64; ++k) d += ro[bb * 64 + k] * ldf(W_dec, k * 64 + h, f32);
    dec[t] = tanhf(d);
  }
  __syncthreads();
  if (t < kB * kA) {
    int bb = t / kA, a = t % kA;
    float m = ldf(b_mean, a, f32), l = ldf(b_ls, a, f32);
    for (int k = 0; k < 64; ++k) {
      float dv = dec[bb * 64 + k];
      m += dv * ldf(W_mean, k * kA + a, f32);
      l += dv * ldf(W_ls, k * kA + a, f32);
    }
    l = fminf(fmaxf(l, -5.f), 2.f);
    stf(out, t, m, f32);            // mean[2][18]
    stf(out, kB * kA + t, l, f32);  // log_std[2][18]
  }
}

extern "C" void kernel_launch(void* const* d_in, const int* in_sizes, int n_in,
                              void* d_out, int out_size, void* d_ws, size_t ws_size,
                              hipStream_t stream) {
  (void)in_sizes; (void)n_in; (void)out_size; (void)ws_size;
  const void* obs    = d_in[0];
  const void* state  = d_in[1];
  const void* W_in   = d_in[2];
  const void* b_in   = d_in[3];
  const void* W_msg  = d_in[4];
  const void* W_gate = d_in[5];
  const void* b_gate = d_in[6];
  const void* W_cand = d_in[7];
  const void* b_cand = d_in[8];
  const void* W_dec  = d_in[9];
  const void* b_dec  = d_in[10];
  const void* W_mean = d_in[11];
  const void* b_mean = d_in[12];
  const void* W_ls   = d_in[13];
  const void* b_ls   = d_in[14];
  const int* src = (const int*)d_in[15];
  const int* dst = (const int*)d_in[16];
  const int* aff = (const int*)d_in[17];
  const int* eff = (const int*)d_in[18];

  // workspace layout (~43 MB)
  int* wsp        = (int*)d_ws;
  int* flags      = wsp;                    // [N]     (zeroed by k_prep b0)
  int* deg_c      = flags + kN;             // [kChunks*N]; becomes chunk_base in scan3
  int* row_off    = deg_c + kChunks * kN;   // [N+1] -> pad N+64
  int* partials   = row_off + (kN + 64);    // [512]
  int* dflag      = partials + 512;         // [16]
  float* projected = (float*)(dflag + 16);           // [128]
  float* eff_acc   = projected + 128;                // [8*128] (zeroed by prep b0)
  int* sorted_src  = (int*)(eff_acc + 1024);         // [E]
  unsigned int* pk  = (unsigned int*)(sorted_src + kE);  // [N*H]
  unsigned int* agg = pk + kNH;                          // [N*H]
  unsigned short* wt = (unsigned short*)(agg + kNH);     // [20480] bf16

  k_prep<<<1 + kHistB + kWprepBlocks, 1024, 0, stream>>>(
      (const unsigned short*)W_cand, obs, W_in, b_in, aff, dst,
      W_msg, W_gate, W_cand, dflag, flags, projected, deg_c, wt, eff_acc);
  k_scan1<<<kScanB, 256, 0, stream>>>(deg_c, row_off, partials);
  k_scan3<<<kScanB, 256, 0, stream>>>(row_off, partials, deg_c);
  k_scatter<<<kHistB + kPackBlocks, 1024, 0, stream>>>(
      src, dst, deg_c, sorted_src, (const unsigned short*)W_cand, state, pk);
  k_gather<<<kGatB, 256, 0, stream>>>(pk, row_off, sorted_src, agg);
  k_update<<<kUpdB, 64, 0, stream>>>(pk, wt, b_gate, b_cand,
                                     agg, flags, projected, dflag, d_out,
                                     eff, eff_acc);
  k_readout<<<1, 128, 0, stream>>>(W_dec, b_dec, W_mean, b_mean, W_ls, b_ls,
                                   eff_acc, dflag, d_out);
}

// Round 14
// 263.181 us; speedup vs baseline: 1.0302x; 1.0302x over previous
//
#include <hip/hip_runtime.h>
#include <hip/hip_bf16.h>

// Problem constants (WholeBrainRateModel)
constexpr int kN   = 50000;    // nodes
constexpr int kH   = 64;       // hidden
constexpr int kB   = 2;        // batch
constexpr int kE   = 1000000;  // edges
constexpr int kObs = 128;
constexpr int kA   = 18;
constexpr int kAff = 512;
constexpr int kEff = 256;
constexpr int kNH  = kN * kH;
constexpr int kOutOff = 2 * kB * kA;  // 72 elements: mean+log_std before next_state
constexpr int kRanges = 8;                // node ranges (bid&7 -> XCD heuristic)
constexpr int kNr  = kN / kRanges;        // 6250 nodes per range (25 KB LDS)
constexpr int kChunks = 64;               // edge chunks
constexpr int kEc  = kE / kChunks;        // 15625 edges per chunk
constexpr int kHistB = kRanges * kChunks; // 512 hist/scatter blocks (1024 thr)
constexpr int kPackPerR = (kNr + 127) / 128;      // 49 pack blocks per range
constexpr int kPackBlocks = kRanges * kPackPerR;  // 392 (range-aligned)
constexpr int kWprepBlocks = 20;                  // 20480 / 1024
constexpr int kScanB = (kN + 255) / 256;          // 196 (1 node/thread)
constexpr int kGatB = kRanges * 1563;             // 12504 (range-aligned gather)
constexpr int kUpdPerR = (kNr + 31) / 32;         // 196 update blocks per range
constexpr int kUpdB = kRanges * kUpdPerR;         // 1568 (range-aligned)

typedef __attribute__((ext_vector_type(8))) short short8_t;  // 8 bf16 (4 VGPRs)
typedef __attribute__((ext_vector_type(4))) float f32x4_t;

// dtype-adaptive load/store (flag==1 -> float32 buffers, else bf16).
__device__ __forceinline__ float ldf(const void* p, int i, int f32) {
  if (f32) return ((const float*)p)[i];
  unsigned short u = ((const unsigned short*)p)[i];
  union { unsigned int x; float f; } v; v.x = ((unsigned int)u) << 16; return v.f;
}
__device__ __forceinline__ void stf(void* p, int i, float val, int f32) {
  if (f32) ((float*)p)[i] = val;
  else ((__hip_bfloat16*)p)[i] = __float2bfloat16(val);
}
__device__ __forceinline__ float lo16(unsigned int w) {
  union { unsigned int i; float f; } v; v.i = w << 16; return v.f;
}
__device__ __forceinline__ float hi16(unsigned int w) {
  union { unsigned int i; float f; } v; v.i = w & 0xffff0000u; return v.f;
}
__device__ __forceinline__ float b2f(unsigned short u) {
  union { unsigned int i; float f; } v; v.i = ((unsigned int)u) << 16; return v.f;
}
__device__ __forceinline__ unsigned int f2b(float f) {  // rne bf16 bits
  union { float f; unsigned int u; } v; v.f = f;
  unsigned int r = v.u + 0x7fffu + ((v.u >> 16) & 1u);
  return r >> 16;
}
// fast transcendentals: v_exp_f32 + v_rcp_f32; error ~1e-6 rel, far below the
// bf16 rounding already present in the pipeline (absmax budget ~2e-3).
__device__ __forceinline__ float fsig(float x) {
  return __builtin_amdgcn_rcpf(1.f + __expf(-x));
}
__device__ __forceinline__ float ftanh(float x) {
  return 1.f - 2.f * __builtin_amdgcn_rcpf(__expf(2.f * x) + 1.f);
}
// wave-0 dtype detector (identical data in every block -> identical answer)
__device__ __forceinline__ int detect64(const unsigned short* wprobe, int t) {
  int hits = 0;
  for (int k = 0; k < 4; ++k) {
    unsigned short u = wprobe[(t * 4 + k) * 2];
    int e = (u >> 7) & 0xFF;
    if ((u & 0x7FFFu) != 0 && e >= 108 && e <= 128) hits++;
  }
  for (int off = 32; off; off >>= 1) hits += __shfl_down(hits, off);
  return (hits < 128) ? 1 : 0;  // few plausible-bf16 => f32
}

// --- fused prep (1024 thr): b0 = detect+flags+proj; b1..512 = hist; wprep ---
// Histogram with ZERO global atomics (rounds 3/4: every global atomic costs a
// ~32 B EA write packet; 1M of them = ~32 MB + 45+ us). Round 5 lesson: keep
// >=2 blk/CU and short per-thread loops. Block (r,c) LDS-counts chunk c's
// edges landing in range r, then plain coalesced stores to deg_c[c][range r].
extern "C" __global__ __launch_bounds__(1024) void k_prep(
    const unsigned short* __restrict__ wprobe,
    const void* __restrict__ obs,
    const void* __restrict__ W_in,
    const void* __restrict__ b_in,
    const int* __restrict__ aff_idx,
    const int* __restrict__ dst,
    const void* __restrict__ W_msg,
    const void* __restrict__ W_gate,
    const void* __restrict__ W_cand,
    int* __restrict__ dflag,
    int* __restrict__ flags,
    float* __restrict__ projected,
    int* __restrict__ deg_c,
    unsigned short* __restrict__ wt,
    float* __restrict__ eff_acc) {
  __shared__ int sdeg[kNr];
  int t = threadIdx.x, b = blockIdx.x;
  if (b == 0) {
    __shared__ int sflag;
    if (t < 64) { int f = detect64(wprobe, t); if (t == 0) { sflag = f; dflag[0] = f; } }
    for (int i = t; i < kN; i += 1024) flags[i] = 0;
    eff_acc[t] = 0.f;                      // 8 range slices x 128
    __syncthreads();
    int f32 = sflag;
    if (t < kAff) flags[aff_idx[t]] = 1;
    if (t < kB * kH) {
      int bb = t >> 6, h = t & 63;
      float acc = ldf(b_in, h, f32);
      for (int o = 0; o < kObs; ++o)
        acc += ldf(obs, bb * kObs + o, f32) * ldf(W_in, o * kH + h, f32);
      projected[t] = acc;
    }
  } else if (b <= kHistB) {
    int h = b - 1, r = h & 7, c = h >> 3;
    int r0 = r * kNr;
    for (int i = t; i < kNr; i += 1024) sdeg[i] = 0;
    __syncthreads();
    int end = (c + 1) * kEc;
    for (int e = c * kEc + t; e < end; e += 1024) {
      unsigned rel = (unsigned)(dst[e] - r0);
      if (rel < (unsigned)kNr) atomicAdd(&sdeg[rel], 1);  // LDS atomic only
    }
    __syncthreads();
    for (int i = t; i < kNr; i += 1024) deg_c[c * kN + r0 + i] = sdeg[i];
  } else {
    __shared__ int sflag;
    if (t < 64) { int f = detect64(wprobe, t); if (t == 0) sflag = f; }
    __syncthreads();
    int f32 = sflag;
    int i = (b - 1 - kHistB) * 1024 + t;  // 0..20479
    if (i < 4096) {
      int n = i >> 6, k = i & 63;
      wt[i] = (unsigned short)f2b(ldf(W_msg, k * 64 + n, f32));
    } else if (i < 12288) {
      int j = i - 4096; int n = j >> 7, k = j & 127;
      wt[i] = (unsigned short)f2b(ldf(W_gate, k * 64 + n, f32));
    } else if (i < 20480) {
      int j = i - 12288; int n = j >> 7, k = j & 127;
      wt[i] = (unsigned short)f2b(ldf(W_cand, k * 64 + n, f32));
    }
  }
}

// --- scan: 196 blocks x 256 thr, 1 node/thread ------------------------------
extern "C" __global__ void k_scan1(const int* __restrict__ deg_c,
                                   int* __restrict__ row_off,
                                   int* __restrict__ partials) {
  __shared__ int sd[256];
  int t = threadIdx.x;
  int n = blockIdx.x * 256 + t;
  int s = 0;
  if (n < kN) {
    for (int c = 0; c < kChunks; ++c) s += deg_c[c * kN + n];
  }
  sd[t] = s;
  __syncthreads();
  for (int off = 1; off < 256; off <<= 1) {
    int v = (t >= off) ? sd[t - off] : 0;
    __syncthreads();
    sd[t] += v;
    __syncthreads();
  }
  int excl = sd[t] - s;
  if (t == 255) partials[blockIdx.x] = sd[255];
  if (n < kN) row_off[n] = excl;
}

// scan2 folded in; additionally transforms deg_c in place into
// chunk_base[c][n] = row_off[n] + sum_{c'<c} deg_c[c'][n]  (atomic-free
// scatter positions). Each node column is owned by exactly one thread.
extern "C" __global__ void k_scan3(int* __restrict__ row_off,
                                   const int* __restrict__ partials,
                                   int* __restrict__ deg_c) {
  __shared__ int sd[256];
  int t = threadIdx.x;
  int s = 0;
  for (int j = t; j < (int)blockIdx.x; j += 256) s += partials[j];
  sd[t] = s;
  __syncthreads();
  for (int off = 128; off; off >>= 1) {
    if (t < off) sd[t] += sd[t + off];
    __syncthreads();
  }
  int base = sd[0];
  int n = blockIdx.x * 256 + t;
  if (n < kN) {
    int v = row_off[n] + base;
    row_off[n] = v;
    int run = v;
#pragma unroll 8
    for (int c = 0; c < kChunks; ++c) {
      int d = deg_c[c * kN + n];
      deg_c[c * kN + n] = run;   // in-place: deg -> chunk_base
      run += d;
    }
  }
  if (blockIdx.x == 0 && t == 0) row_off[kN] = kE;
}

// --- scatter (+pack riding along), 1024 thr: ZERO global atomics ------------
// Block (r,c): load range r's chunk_base slice into an LDS cursor, then for
// chunk c's in-range edges take slots via LDS atomicAdd and store. Slots are
// disjoint across chunks by construction (chunk_base prefix). bid&7 = r keeps
// each range's ~500 KB sorted_src window written by one XCD (L2 locality).
// Pack blocks (bid >= 512): range-aligned: pack block p handles nodes of
// range p&7 -> pk's range-r lines are written by XCD r's L2.
extern "C" __global__ __launch_bounds__(1024) void k_scatter(
    const int* __restrict__ src,
    const int* __restrict__ dst,
    const int* __restrict__ chunk_base,
    int* __restrict__ sorted_src,
    const unsigned short* __restrict__ wprobe,
    const void* __restrict__ state,
    unsigned int* __restrict__ pack) {
  __shared__ int scur[kNr];
  int t = threadIdx.x;
  if (blockIdx.x < kHistB) {
    int r = blockIdx.x & 7, c = blockIdx.x >> 3;
    int r0 = r * kNr;
    for (int i = t; i < kNr; i += 1024) scur[i] = chunk_base[c * kN + r0 + i];
    __syncthreads();
    int end = (c + 1) * kEc;
    for (int e = c * kEc + t; e < end; e += 1024) {
      unsigned rel = (unsigned)(dst[e] - r0);
      if (rel < (unsigned)kNr) {
        int pos = atomicAdd(&scur[rel], 1);   // LDS atomic only
        sorted_src[pos] = src[e];
      }
    }
  } else {
    __shared__ int sflag;
    if (t < 64) { int f = detect64(wprobe, t); if (t == 0) sflag = f; }
    __syncthreads();
    int f32 = sflag;
    int p = blockIdx.x - kHistB;           // kHistB = 512 (div by 8): XCD = p&7
    int x = p & 7, j = p >> 3;
    int nb = x * kNr + j * 128;            // first node of this pack block
    int nl = min(nb + 128, (x + 1) * kNr); // range-local node limit
    int i = nb * 64 + t * 8;               // 8 elems/thread
    if (i < nl * 64) {
      uint4 o0, o1;
      if (!f32) {
        // bf16 inputs: pack is a pure bit-interleave (no rounding round-trip)
        uint4 a = *(const uint4*)((const unsigned short*)state + i);
        uint4 c4 = *(const uint4*)((const unsigned short*)state + kNH + i);
        o0.x = (a.x & 0xffffu) | (c4.x << 16);
        o0.y = (a.x >> 16)     | (c4.x & 0xffff0000u);
        o0.z = (a.y & 0xffffu) | (c4.y << 16);
        o0.w = (a.y >> 16)     | (c4.y & 0xffff0000u);
        o1.x = (a.z & 0xffffu) | (c4.z << 16);
        o1.y = (a.z >> 16)     | (c4.z & 0xffff0000u);
        o1.z = (a.w & 0xffffu) | (c4.w << 16);
        o1.w = (a.w >> 16)     | (c4.w & 0xffff0000u);
      } else {
        const float* sf = (const float*)state;
        unsigned int w[8];
#pragma unroll
        for (int k = 0; k < 8; ++k)
          w[k] = f2b(sf[i + k]) | (f2b(sf[kNH + i + k]) << 16);
        o0 = make_uint4(w[0], w[1], w[2], w[3]);
        o1 = make_uint4(w[4], w[5], w[6], w[7]);
      }
      *(uint4*)&pack[i] = o0;
      *(uint4*)&pack[i + 4] = o1;
    }
  }
}

// --- gather: one wave per node over its contiguous edge span ----------------
// XCD-range-aligned grid: bid&7 = node range r, so this block runs on the
// SAME XCD (bid%8 heuristic) whose L2 wrote range r's sorted_src in
// k_scatter -> span reads hit dirty-local lines instead of migrating them.
// 16-lane groups: group g handles edge e+g (and e+4+g), lane loads uint4
// (16 B = 4 packed h-columns). Cross-group shfl_xor(16/32) reduce at the end.
extern "C" __global__ __launch_bounds__(256) void k_gather(
    const unsigned int* __restrict__ pack,
    const int* __restrict__ row_off,     // span = [off[n], off[n+1])
    const int* __restrict__ sorted_src,
    unsigned int* __restrict__ agg) {
  int wave = threadIdx.x >> 6, lane = threadIdx.x & 63;
  int x = blockIdx.x & 7, j = blockIdx.x >> 3;
  int local = j * 4 + wave;
  if (local >= kNr) return;
  int n = x * kNr + local;
  int s  = row_off[n];
  int en = row_off[n + 1];
  int g = lane >> 4, col = lane & 15;
  const uint4* pk4 = (const uint4*)pack;
  float a0x = 0.f, a0y = 0.f, a0z = 0.f, a0w = 0.f;
  float a1x = 0.f, a1y = 0.f, a1z = 0.f, a1w = 0.f;
  for (int e = s; e < en; e += 8) {
#pragma unroll
    for (int h = 0; h < 2; ++h) {
      int ee = e + h * 4 + g;
      int idx = sorted_src[min(ee, en - 1)];
      uint4 wv = pk4[idx * 16 + col];
      if (ee >= en) { wv.x = 0u; wv.y = 0u; wv.z = 0u; wv.w = 0u; }
      a0x += lo16(wv.x); a1x += hi16(wv.x);
      a0y += lo16(wv.y); a1y += hi16(wv.y);
      a0z += lo16(wv.z); a1z += hi16(wv.z);
      a0w += lo16(wv.w); a1w += hi16(wv.w);
    }
  }
  // reduce the 4 edge-groups (lanes differing in bits 4,5) onto group 0
  a0x += __shfl_xor(a0x, 16); a0x += __shfl_xor(a0x, 32);
  a0y += __shfl_xor(a0y, 16); a0y += __shfl_xor(a0y, 32);
  a0z += __shfl_xor(a0z, 16); a0z += __shfl_xor(a0z, 32);
  a0w += __shfl_xor(a0w, 16); a0w += __shfl_xor(a0w, 32);
  a1x += __shfl_xor(a1x, 16); a1x += __shfl_xor(a1x, 32);
  a1y += __shfl_xor(a1y, 16); a1y += __shfl_xor(a1y, 32);
  a1z += __shfl_xor(a1z, 16); a1z += __shfl_xor(a1z, 32);
  a1w += __shfl_xor(a1w, 16); a1w += __shfl_xor(a1w, 32);
  if (g == 0) {
    uint4 o;
    o.x = f2b(a0x) | (f2b(a1x) << 16);
    o.y = f2b(a0y) | (f2b(a1y) << 16);
    o.z = f2b(a0z) | (f2b(a1z) << 16);
    o.w = f2b(a0w) | (f2b(a1w) << 16);
    ((uint4*)agg)[n * 16 + col] = o;
  }
}

// --- update (MFMA) + eff accumulation (NO fence) ----------------------------
// ROUND-14: exact revert to the round-12 form (best measured total, 257 us);
// four structural variants (4-wave 25%/50% occ, range-aligned, 1-wave
// autonomous) all measured 44-45 us with every engine <13% busy -> the
// kernel is per-wave dependent-chain latency-bound and insensitive to these
// levers. Only kept delta vs round 12: per-RANGE eff_acc slices (8x less
// atomic contention in the tail; no fence — kernel boundary is the one
// cross-XCD flush, round-10 lesson).
extern "C" __global__ __launch_bounds__(256) void k_update(
    const unsigned int* __restrict__ pk,
    const unsigned short* __restrict__ wt,   // prepped bf16 Wt msg|gate|cand
    const void* __restrict__ b_gate,
    const void* __restrict__ b_cand,
    const unsigned int* __restrict__ agg,
    const int* __restrict__ flags,
    const float* __restrict__ projected,
    const int* __restrict__ dflag,
    void* __restrict__ out,
    const int* __restrict__ eff_idx,
    float* __restrict__ eff_acc) {
  __shared__ uint4 lx4[1088];    // 17408 B = 4 wave strips of 16 rows x 272 B
  __shared__ int smatch[256];
  __shared__ int smcnt;
  unsigned short* lx = (unsigned short*)lx4;
  int f32 = dflag[0];
  int t = threadIdx.x;
  int w = t >> 6, lane = t & 63;
  int q = lane >> 4, l15 = lane & 15;
  int rowb = w * 16;
  int x = blockIdx.x & 7, jb = blockIdx.x >> 3;
  int nd0 = x * kNr + jb * 32;
  int rend = (x + 1) * kNr;        // range-local node limit
  if (nd0 >= rend) return;
  int ndw = nd0 + w * 8;           // wave's first node
  if (t == 0) smcnt = 0;

  const uint4* pk4 = (const uint4*)pk;
  const uint4* ag4 = (const uint4*)agg;
  // wave-private staging: state -> cols 0-63, agg -> cols 64-127 (own 8 nodes)
  for (int j = lane; j < 128; j += 64) {
    int ndl = j >> 4, c4 = j & 15;
    int ndg = min(ndw + ndl, rend - 1);
    uint4 pv = pk4[ndg * 16 + c4];
    uint4 av = ag4[ndg * 16 + c4];
    int r0 = rowb + 2 * ndl;
    *(uint2*)&lx[r0 * 136 + c4 * 4] =
        make_uint2((pv.x & 0xffffu) | (pv.y << 16), (pv.z & 0xffffu) | (pv.w << 16));
    *(uint2*)&lx[(r0 + 1) * 136 + c4 * 4] =
        make_uint2((pv.x >> 16) | (pv.y & 0xffff0000u), (pv.z >> 16) | (pv.w & 0xffff0000u));
    *(uint2*)&lx[r0 * 136 + 64 + c4 * 4] =
        make_uint2((av.x & 0xffffu) | (av.y << 16), (av.z & 0xffffu) | (av.w << 16));
    *(uint2*)&lx[(r0 + 1) * 136 + 64 + c4 * 4] =
        make_uint2((av.x >> 16) | (av.y & 0xffff0000u), (av.z >> 16) | (av.w & 0xffff0000u));
  }

  const unsigned short* wm = wt;            // msg^T  [64][64]  (row = out col)
  const unsigned short* wg = wt + 4096;     // gate^T [64][128]
  const unsigned short* wc = wt + 12288;    // cand^T [64][128]

  // --- msg phase: C[16x64] = agg[16x64] @ W_msg[64x64] ---
  short8_t a0 = *(const short8_t*)&lx[(rowb + l15) * 136 + 64 + q * 8];
  short8_t a1 = *(const short8_t*)&lx[(rowb + l15) * 136 + 96 + q * 8];
  f32x4_t msgc[4];
#pragma unroll
  for (int ct = 0; ct < 4; ++ct) {
    f32x4_t acc = {0.f, 0.f, 0.f, 0.f};
    short8_t b0 = *(const short8_t*)&wm[(ct * 16 + l15) * 64 + q * 8];
    short8_t b1 = *(const short8_t*)&wm[(ct * 16 + l15) * 64 + 32 + q * 8];
    acc = __builtin_amdgcn_mfma_f32_16x16x32_bf16(a0, b0, acc, 0, 0, 0);
    acc = __builtin_amdgcn_mfma_f32_16x16x32_bf16(a1, b1, acc, 0, 0, 0);
    msgc[ct] = acc;
  }
  // combined = msg + inject -> back into X cols 64-127 (own strip rows only)
  int nA = ndw + q * 2, nB = nA + 1;
  int flA = (nA < rend) ? flags[nA] : 0;
  int flB = (nB < rend) ? flags[nB] : 0;
#pragma unroll
  for (int ct = 0; ct < 4; ++ct) {
    int col = ct * 16 + l15;
    float pj0 = projected[col], pj1 = projected[64 + col];
#pragma unroll
    for (int r = 0; r < 4; ++r) {
      int row = rowb + q * 4 + r;
      int fl = (r < 2) ? flA : flB;
      float inj = fl ? ((row & 1) ? pj1 : pj0) : 0.f;
      lx[row * 136 + 64 + col] = (unsigned short)f2b(msgc[ct][r] + inj);
    }
  }

  // --- gate/cand phase: K=128 over [state | combined] ---
  short8_t xa[4];
#pragma unroll
  for (int ks = 0; ks < 4; ++ks)
    xa[ks] = *(const short8_t*)&lx[(rowb + l15) * 136 + ks * 32 + q * 8];
  // prev-state (own rows) to regs BEFORE result staging overwrites the strip
  float ps[16];
#pragma unroll
  for (int ct = 0; ct < 4; ++ct)
#pragma unroll
    for (int rp = 0; rp < 2; ++rp) {
      int row = rowb + q * 4 + 2 * rp;
      ps[ct * 4 + rp * 2 + 0] = b2f(lx[row * 136 + ct * 16 + l15]);
      ps[ct * 4 + rp * 2 + 1] = b2f(lx[(row + 1) * 136 + ct * 16 + l15]);
    }
  // per-wave result staging: strip w reused as [16 rows][64] f32 (4096 B)
  float* soutw = (float*)((char*)lx4 + w * 4352);
#pragma unroll
  for (int ct = 0; ct < 4; ++ct) {
    f32x4_t accg = {0.f, 0.f, 0.f, 0.f}, accc = {0.f, 0.f, 0.f, 0.f};
#pragma unroll
    for (int ks = 0; ks < 4; ++ks) {
      short8_t bg = *(const short8_t*)&wg[(ct * 16 + l15) * 128 + ks * 32 + q * 8];
      short8_t bc = *(const short8_t*)&wc[(ct * 16 + l15) * 128 + ks * 32 + q * 8];
      accg = __builtin_amdgcn_mfma_f32_16x16x32_bf16(xa[ks], bg, accg, 0, 0, 0);
      accc = __builtin_amdgcn_mfma_f32_16x16x32_bf16(xa[ks], bc, accc, 0, 0, 0);
    }
    int col = ct * 16 + l15;
    float bgv = ldf(b_gate, col, f32), bcv = ldf(b_cand, col, f32);
#pragma unroll
    for (int rp = 0; rp < 2; ++rp) {
      int r = q * 4 + 2 * rp;   // local strip row (batch0); r+1 = batch1
      float z0 = fsig(accg[2 * rp] + bgv);
      float c0 = ftanh(accc[2 * rp] + bcv);
      soutw[r * 64 + col] = (1.f - z0) * ps[ct * 4 + rp * 2 + 0] + z0 * c0;
      float z1 = fsig(accg[2 * rp + 1] + bgv);
      float c1 = ftanh(accc[2 * rp + 1] + bcv);
      soutw[(r + 1) * 64 + col] = (1.f - z1) * ps[ct * 4 + rp * 2 + 1] + z1 * c1;
    }
  }
  __syncthreads();

  // eff-membership scan (256 entries, L2-hot; duplicates counted per entry)
  int nlim = min(32, rend - nd0);
  if (t < kEff) {
    unsigned rel = (unsigned)(eff_idx[t] - nd0);
    if (rel < (unsigned)nlim) { int s = atomicAdd(&smcnt, 1); smatch[s] = (int)rel; }
  }
  __syncthreads();

  // block-linear aligned copy-out (16B-aligned: 288 and 144 are both /16)
  int nvalid = nlim * 64;   // elements per plane (multiple of 64)
  if (f32) {
    float* po = (float*)out + kOutOff;
#pragma unroll
    for (int p = 0; p < 2; ++p)
      for (int j = t * 4; j < nvalid; j += 1024) {
        int ndl = j >> 6, c = j & 63;
        int wv = ndl >> 3, r = ((ndl & 7) << 1) + p;
        float4 v = *(float4*)((char*)lx4 + wv * 4352 + r * 256 + c * 4);
        *(float4*)(po + p * kNH + nd0 * 64 + j) = v;
      }
  } else {
    unsigned short* po = (unsigned short*)out + kOutOff;
#pragma unroll
    for (int p = 0; p < 2; ++p)
      for (int j = t * 8; j < nvalid; j += 2048) {
        int ndl = j >> 6, c = j & 63;
        int wv = ndl >> 3, r = ((ndl & 7) << 1) + p;
        const char* base = (const char*)lx4 + wv * 4352 + r * 256 + c * 4;
        float4 v0 = *(const float4*)base;
        float4 v1 = *(const float4*)(base + 16);
        uint4 o;
        o.x = f2b(v0.x) | (f2b(v0.y) << 16);
        o.y = f2b(v0.z) | (f2b(v0.w) << 16);
        o.z = f2b(v1.x) | (f2b(v1.y) << 16);
        o.w = f2b(v1.z) | (f2b(v1.w) << 16);
        *(uint4*)(po + p * kNH + nd0 * 64 + j) = o;
      }
  }

  // accumulate matched eff rows into the per-range slice (t<128: (p,c))
  int cnt = smcnt;
  for (int m = 0; m < cnt; ++m) {
    int rel = smatch[m];
    if (t < 128) {
      int p = t >> 6, c = t & 63;
      int wv = rel >> 3, r = ((rel & 7) << 1) + p;
      float v = *(const float*)((const char*)lx4 + wv * 4352 + r * 256 + c * 4);
      if (!f32) v = b2f((unsigned short)f2b(v));   // match stored precision
      atomicAdd(&eff_acc[x * 128 + p * 64 + c], v);  // device-scope, no fence
    }
  }
}

// --- readout: tiny decode + policy heads from per-range eff_acc slices ------
// Kernel boundary provides cross-XCD visibility of k_update's eff_acc atomics
// (one command-processor flush instead of per-block fences — round 10).
extern "C" __global__ void k_readout(const void* __restrict__ W_dec,
                                     const void* __restrict__ b_dec,
                                     const void* __restrict__ W_mean,
                                     const void* __restrict__ b_mean,
                                     const void* __restrict__ W_ls,
                                     const void* __restrict__ b_ls,
                                     const float* __restrict__ eff_acc,
                                     const int* __restrict__ dflag,
                                     void* __restrict__ out) {
  __shared__ float ro[128], dec[128];
  int f32 = dflag[0];
  int t = threadIdx.x;            // 128 threads
  if (t < 128) {
    float s = 0.f;
#pragma unroll
    for (int r = 0; r < kRanges; ++r) s += eff_acc[r * 128 + t];
    ro[t] = s * (1.f / kEff);
  }
  __syncthreads();
  if (t < 128) {
    int bb = t >> 6, h = t & 63;
    float d = ldf(b_dec, h, f32);
    for (int k = 0; k < 64; ++k) d += ro[bb * 64 + k] * ldf(W_dec, k * 64 + h, f32);
    dec[t] = tanhf(d);
  }
  __syncthreads();
  if (t < kB * kA) {
    int bb = t / kA, a = t % kA;
    float m = ldf(b_mean, a, f32), l = ldf(b_ls, a, f32);
    for (int k = 0; k < 64; ++k) {
      float dv = dec[bb * 64 + k];
      m += dv * ldf(W_mean, k * kA + a, f32);
      l += dv * ldf(W_ls, k * kA + a, f32);
    }
    l = fminf(fmaxf(l, -5.f), 2.f);
    stf(out, t, m, f32);            // mean[2][18]
    stf(out, kB * kA + t, l, f32);  // log_std[2][18]
  }
}

extern "C" void kernel_launch(void* const* d_in, const int* in_sizes, int n_in,
                              void* d_out, int out_size, void* d_ws, size_t ws_size,
                              hipStream_t stream) {
  (void)in_sizes; (void)n_in; (void)out_size; (void)ws_size;
  const void* obs    = d_in[0];
  const void* state  = d_in[1];
  const void* W_in   = d_in[2];
  const void* b_in   = d_in[3];
  const void* W_msg  = d_in[4];
  const void* W_gate = d_in[5];
  const void* b_gate = d_in[6];
  const void* W_cand = d_in[7];
  const void* b_cand = d_in[8];
  const void* W_dec  = d_in[9];
  const void* b_dec  = d_in[10];
  const void* W_mean = d_in[11];
  const void* b_mean = d_in[12];
  const void* W_ls   = d_in[13];
  const void* b_ls   = d_in[14];
  const int* src = (const int*)d_in[15];
  const int* dst = (const int*)d_in[16];
  const int* aff = (const int*)d_in[17];
  const int* eff = (const int*)d_in[18];

  // workspace layout (~43 MB)
  int* wsp        = (int*)d_ws;
  int* flags      = wsp;                    // [N]     (zeroed by k_prep b0)
  int* deg_c      = flags + kN;             // [kChunks*N]; becomes chunk_base in scan3
  int* row_off    = deg_c + kChunks * kN;   // [N+1] -> pad N+64
  int* partials   = row_off + (kN + 64);    // [512]
  int* dflag      = partials + 512;         // [16]
  float* projected = (float*)(dflag + 16);           // [128]
  float* eff_acc   = projected + 128;                // [8*128] (zeroed by prep b0)
  int* sorted_src  = (int*)(eff_acc + 1024);         // [E]
  unsigned int* pk  = (unsigned int*)(sorted_src + kE);  // [N*H]
  unsigned int* agg = pk + kNH;                          // [N*H]
  unsigned short* wt = (unsigned short*)(agg + kNH);     // [20480] bf16

  k_prep<<<1 + kHistB + kWprepBlocks, 1024, 0, stream>>>(
      (const unsigned short*)W_cand, obs, W_in, b_in, aff, dst,
      W_msg, W_gate, W_cand, dflag, flags, projected, deg_c, wt, eff_acc);
  k_scan1<<<kScanB, 256, 0, stream>>>(deg_c, row_off, partials);
  k_scan3<<<kScanB, 256, 0, stream>>>(row_off, partials, deg_c);
  k_scatter<<<kHistB + kPackBlocks, 1024, 0, stream>>>(
      src, dst, deg_c, sorted_src, (const unsigned short*)W_cand, state, pk);
  k_gather<<<kGatB, 256, 0, stream>>>(pk, row_off, sorted_src, agg);
  k_update<<<kUpdB, 256, 0, stream>>>(pk, wt, b_gate, b_cand,
                                      agg, flags, projected, dflag, d_out,
                                      eff, eff_acc);
  k_readout<<<1, 128, 0, stream>>>(W_dec, b_dec, W_mean, b_mean, W_ls, b_ls,
                                   eff_acc, dflag, d_out);
}

// Round 15
// 253.704 us; speedup vs baseline: 1.0687x; 1.0374x over previous
//
#include <hip/hip_runtime.h>
#include <hip/hip_bf16.h>

// Problem constants (WholeBrainRateModel)
constexpr int kN   = 50000;    // nodes
constexpr int kH   = 64;       // hidden
constexpr int kB   = 2;        // batch
constexpr int kE   = 1000000;  // edges
constexpr int kObs = 128;
constexpr int kA   = 18;
constexpr int kAff = 512;
constexpr int kEff = 256;
constexpr int kNH  = kN * kH;
constexpr int kOutOff = 2 * kB * kA;  // 72 elements: mean+log_std before next_state
constexpr int kRanges = 8;                // node ranges (bid&7 -> XCD heuristic)
constexpr int kNr  = kN / kRanges;        // 6250 nodes per range (25 KB LDS)
constexpr int kChunks = 64;               // edge chunks
constexpr int kEc  = kE / kChunks;        // 15625 edges per chunk
constexpr int kHistB = kRanges * kChunks; // 512 hist/scatter blocks (1024 thr)
constexpr int kPackPerR = (kNr + 127) / 128;      // 49 pack blocks per range
constexpr int kPackBlocks = kRanges * kPackPerR;  // 392 (range-aligned)
constexpr int kWprepBlocks = 20;                  // 20480 / 1024
constexpr int kScanB = (kN + 255) / 256;          // 196 (1 node/thread)
constexpr int kGuPerR = (kNr + 7) / 8;            // 782 fused blocks per range
constexpr int kGuB = kRanges * kGuPerR;           // 6256 (8 nodes/block)

typedef __attribute__((ext_vector_type(8))) short short8_t;  // 8 bf16 (4 VGPRs)
typedef __attribute__((ext_vector_type(4))) float f32x4_t;

// dtype-adaptive load/store (flag==1 -> float32 buffers, else bf16).
__device__ __forceinline__ float ldf(const void* p, int i, int f32) {
  if (f32) return ((const float*)p)[i];
  unsigned short u = ((const unsigned short*)p)[i];
  union { unsigned int x; float f; } v; v.x = ((unsigned int)u) << 16; return v.f;
}
__device__ __forceinline__ void stf(void* p, int i, float val, int f32) {
  if (f32) ((float*)p)[i] = val;
  else ((__hip_bfloat16*)p)[i] = __float2bfloat16(val);
}
__device__ __forceinline__ float lo16(unsigned int w) {
  union { unsigned int i; float f; } v; v.i = w << 16; return v.f;
}
__device__ __forceinline__ float hi16(unsigned int w) {
  union { unsigned int i; float f; } v; v.i = w & 0xffff0000u; return v.f;
}
__device__ __forceinline__ float b2f(unsigned short u) {
  union { unsigned int i; float f; } v; v.i = ((unsigned int)u) << 16; return v.f;
}
__device__ __forceinline__ unsigned int f2b(float f) {  // rne bf16 bits
  union { float f; unsigned int u; } v; v.f = f;
  unsigned int r = v.u + 0x7fffu + ((v.u >> 16) & 1u);
  return r >> 16;
}
// fast transcendentals: v_exp_f32 + v_rcp_f32; error ~1e-6 rel, far below the
// bf16 rounding already present in the pipeline (absmax budget ~2e-3).
__device__ __forceinline__ float fsig(float x) {
  return __builtin_amdgcn_rcpf(1.f + __expf(-x));
}
__device__ __forceinline__ float ftanh(float x) {
  return 1.f - 2.f * __builtin_amdgcn_rcpf(__expf(2.f * x) + 1.f);
}
// wave-0 dtype detector (identical data in every block -> identical answer)
__device__ __forceinline__ int detect64(const unsigned short* wprobe, int t) {
  int hits = 0;
  for (int k = 0; k < 4; ++k) {
    unsigned short u = wprobe[(t * 4 + k) * 2];
    int e = (u >> 7) & 0xFF;
    if ((u & 0x7FFFu) != 0 && e >= 108 && e <= 128) hits++;
  }
  for (int off = 32; off; off >>= 1) hits += __shfl_down(hits, off);
  return (hits < 128) ? 1 : 0;  // few plausible-bf16 => f32
}

// --- fused prep (1024 thr): b0 = detect+flags+proj; b1..512 = hist; wprep ---
// Histogram with ZERO global atomics (rounds 3/4: every global atomic costs a
// ~32 B EA write packet; 1M of them = ~32 MB + 45+ us). Round 5 lesson: keep
// >=2 blk/CU and short per-thread loops. Block (r,c) LDS-counts chunk c's
// edges landing in range r, then plain coalesced stores to deg_c[c][range r].
extern "C" __global__ __launch_bounds__(1024) void k_prep(
    const unsigned short* __restrict__ wprobe,
    const void* __restrict__ obs,
    const void* __restrict__ W_in,
    const void* __restrict__ b_in,
    const int* __restrict__ aff_idx,
    const int* __restrict__ dst,
    const void* __restrict__ W_msg,
    const void* __restrict__ W_gate,
    const void* __restrict__ W_cand,
    int* __restrict__ dflag,
    int* __restrict__ flags,
    float* __restrict__ projected,
    int* __restrict__ deg_c,
    unsigned short* __restrict__ wt,
    float* __restrict__ eff_acc) {
  __shared__ int sdeg[kNr];
  int t = threadIdx.x, b = blockIdx.x;
  if (b == 0) {
    __shared__ int sflag;
    if (t < 64) { int f = detect64(wprobe, t); if (t == 0) { sflag = f; dflag[0] = f; } }
    for (int i = t; i < kN; i += 1024) flags[i] = 0;
    eff_acc[t] = 0.f;                      // 8 range slices x 128
    __syncthreads();
    int f32 = sflag;
    if (t < kAff) flags[aff_idx[t]] = 1;
    if (t < kB * kH) {
      int bb = t >> 6, h = t & 63;
      float acc = ldf(b_in, h, f32);
      for (int o = 0; o < kObs; ++o)
        acc += ldf(obs, bb * kObs + o, f32) * ldf(W_in, o * kH + h, f32);
      projected[t] = acc;
    }
  } else if (b <= kHistB) {
    int h = b - 1, r = h & 7, c = h >> 3;
    int r0 = r * kNr;
    for (int i = t; i < kNr; i += 1024) sdeg[i] = 0;
    __syncthreads();
    int end = (c + 1) * kEc;
    for (int e = c * kEc + t; e < end; e += 1024) {
      unsigned rel = (unsigned)(dst[e] - r0);
      if (rel < (unsigned)kNr) atomicAdd(&sdeg[rel], 1);  // LDS atomic only
    }
    __syncthreads();
    for (int i = t; i < kNr; i += 1024) deg_c[c * kN + r0 + i] = sdeg[i];
  } else {
    __shared__ int sflag;
    if (t < 64) { int f = detect64(wprobe, t); if (t == 0) sflag = f; }
    __syncthreads();
    int f32 = sflag;
    int i = (b - 1 - kHistB) * 1024 + t;  // 0..20479
    if (i < 4096) {
      int n = i >> 6, k = i & 63;
      wt[i] = (unsigned short)f2b(ldf(W_msg, k * 64 + n, f32));
    } else if (i < 12288) {
      int j = i - 4096; int n = j >> 7, k = j & 127;
      wt[i] = (unsigned short)f2b(ldf(W_gate, k * 64 + n, f32));
    } else if (i < 20480) {
      int j = i - 12288; int n = j >> 7, k = j & 127;
      wt[i] = (unsigned short)f2b(ldf(W_cand, k * 64 + n, f32));
    }
  }
}

// --- scan: 196 blocks x 256 thr, 1 node/thread ------------------------------
extern "C" __global__ void k_scan1(const int* __restrict__ deg_c,
                                   int* __restrict__ row_off,
                                   int* __restrict__ partials) {
  __shared__ int sd[256];
  int t = threadIdx.x;
  int n = blockIdx.x * 256 + t;
  int s = 0;
  if (n < kN) {
    for (int c = 0; c < kChunks; ++c) s += deg_c[c * kN + n];
  }
  sd[t] = s;
  __syncthreads();
  for (int off = 1; off < 256; off <<= 1) {
    int v = (t >= off) ? sd[t - off] : 0;
    __syncthreads();
    sd[t] += v;
    __syncthreads();
  }
  int excl = sd[t] - s;
  if (t == 255) partials[blockIdx.x] = sd[255];
  if (n < kN) row_off[n] = excl;
}

// scan2 folded in; additionally transforms deg_c in place into
// chunk_base[c][n] = row_off[n] + sum_{c'<c} deg_c[c'][n]  (atomic-free
// scatter positions). Each node column is owned by exactly one thread.
extern "C" __global__ void k_scan3(int* __restrict__ row_off,
                                   const int* __restrict__ partials,
                                   int* __restrict__ deg_c) {
  __shared__ int sd[256];
  int t = threadIdx.x;
  int s = 0;
  for (int j = t; j < (int)blockIdx.x; j += 256) s += partials[j];
  sd[t] = s;
  __syncthreads();
  for (int off = 128; off; off >>= 1) {
    if (t < off) sd[t] += sd[t + off];
    __syncthreads();
  }
  int base = sd[0];
  int n = blockIdx.x * 256 + t;
  if (n < kN) {
    int v = row_off[n] + base;
    row_off[n] = v;
    int run = v;
#pragma unroll 8
    for (int c = 0; c < kChunks; ++c) {
      int d = deg_c[c * kN + n];
      deg_c[c * kN + n] = run;   // in-place: deg -> chunk_base
      run += d;
    }
  }
  if (blockIdx.x == 0 && t == 0) row_off[kN] = kE;
}

// --- scatter (+pack riding along), 1024 thr: ZERO global atomics ------------
// Block (r,c): load range r's chunk_base slice into an LDS cursor, then for
// chunk c's in-range edges take slots via LDS atomicAdd and store. Slots are
// disjoint across chunks by construction (chunk_base prefix). bid&7 = r keeps
// each range's ~500 KB sorted_src window written by one XCD (L2 locality).
// Pack blocks (bid >= 512): range-aligned: pack block p handles nodes of
// range p&7 -> pk's range-r lines are written by XCD r's L2.
extern "C" __global__ __launch_bounds__(1024) void k_scatter(
    const int* __restrict__ src,
    const int* __restrict__ dst,
    const int* __restrict__ chunk_base,
    int* __restrict__ sorted_src,
    const unsigned short* __restrict__ wprobe,
    const void* __restrict__ state,
    unsigned int* __restrict__ pack) {
  __shared__ int scur[kNr];
  int t = threadIdx.x;
  if (blockIdx.x < kHistB) {
    int r = blockIdx.x & 7, c = blockIdx.x >> 3;
    int r0 = r * kNr;
    for (int i = t; i < kNr; i += 1024) scur[i] = chunk_base[c * kN + r0 + i];
    __syncthreads();
    int end = (c + 1) * kEc;
    for (int e = c * kEc + t; e < end; e += 1024) {
      unsigned rel = (unsigned)(dst[e] - r0);
      if (rel < (unsigned)kNr) {
        int pos = atomicAdd(&scur[rel], 1);   // LDS atomic only
        sorted_src[pos] = src[e];
      }
    }
  } else {
    __shared__ int sflag;
    if (t < 64) { int f = detect64(wprobe, t); if (t == 0) sflag = f; }
    __syncthreads();
    int f32 = sflag;
    int p = blockIdx.x - kHistB;           // kHistB = 512 (div by 8): XCD = p&7
    int x = p & 7, j = p >> 3;
    int nb = x * kNr + j * 128;            // first node of this pack block
    int nl = min(nb + 128, (x + 1) * kNr); // range-local node limit
    int i = nb * 64 + t * 8;               // 8 elems/thread
    if (i < nl * 64) {
      uint4 o0, o1;
      if (!f32) {
        // bf16 inputs: pack is a pure bit-interleave (no rounding round-trip)
        uint4 a = *(const uint4*)((const unsigned short*)state + i);
        uint4 c4 = *(const uint4*)((const unsigned short*)state + kNH + i);
        o0.x = (a.x & 0xffffu) | (c4.x << 16);
        o0.y = (a.x >> 16)     | (c4.x & 0xffff0000u);
        o0.z = (a.y & 0xffffu) | (c4.y << 16);
        o0.w = (a.y >> 16)     | (c4.y & 0xffff0000u);
        o1.x = (a.z & 0xffffu) | (c4.z << 16);
        o1.y = (a.z >> 16)     | (c4.z & 0xffff0000u);
        o1.z = (a.w & 0xffffu) | (c4.w << 16);
        o1.w = (a.w >> 16)     | (c4.w & 0xffff0000u);
      } else {
        const float* sf = (const float*)state;
        unsigned int w[8];
#pragma unroll
        for (int k = 0; k < 8; ++k)
          w[k] = f2b(sf[i + k]) | (f2b(sf[kNH + i + k]) << 16);
        o0 = make_uint4(w[0], w[1], w[2], w[3]);
        o1 = make_uint4(w[4], w[5], w[6], w[7]);
      }
      *(uint4*)&pack[i] = o0;
      *(uint4*)&pack[i + 4] = o1;
    }
  }
}

// --- FUSED gather+update (round 15) -----------------------------------------
// Round-8's fusion failed because it serialized 8 nodes per wave (6252
// gathering waves, 30% occ). This one keeps gather TLP: 8 nodes/block,
// 2 nodes/WAVE (25008 gathering waves, 8 blk/CU = 32 waves/CU), gather
// results written straight into the shared 16-row LDS strip. After ONE
// barrier, wave 0 alone runs the proven 16-row update tile from LDS (waves
// 1-3 exit, freeing slots -> next block's gather waves start: gather and
// update naturally pipeline across blocks). agg buffer + its 25.6 MB HBM
// round-trip + one dispatch eliminated. Weights 40 KB/block from L2
// (6256 x 40 KB = 250 MB L2-hot ~ 7 us aggregate).
extern "C" __global__ __launch_bounds__(256) void k_gupd(
    const unsigned int* __restrict__ pack,
    const int* __restrict__ row_off,     // span = [off[n], off[n+1])
    const int* __restrict__ sorted_src,
    const unsigned short* __restrict__ wt,   // prepped bf16 Wt msg|gate|cand
    const void* __restrict__ b_gate,
    const void* __restrict__ b_cand,
    const int* __restrict__ flags,
    const float* __restrict__ projected,
    const int* __restrict__ dflag,
    void* __restrict__ out,
    const int* __restrict__ eff_idx,
    float* __restrict__ eff_acc) {
  __shared__ uint4 lx4[274];     // 4384 B: strip [16 rows][136 u16]
  __shared__ int smatch[256];
  __shared__ int smcnt;
  unsigned short* lx = (unsigned short*)lx4;
  int t = threadIdx.x;
  int w = t >> 6, lane = t & 63;
  int g = lane >> 4, col = lane & 15;
  int x = blockIdx.x & 7, jb = blockIdx.x >> 3;
  int nd0 = x * kNr + jb * 8;    // block's first node (8 nodes)
  int rend = (x + 1) * kNr;      // range-local node limit
  if (nd0 >= rend) return;
  if (t == 0) smcnt = 0;

  const uint4* pk4 = (const uint4*)pack;

  // --- phase 1 (all 4 waves): stage state + gather own 2 nodes into strip ---
  // stage state cols 0-63 for wave's 2 nodes (lanes 0-31: one uint4 each)
  if (lane < 32) {
    int ndl = 2 * w + (lane >> 4), c4 = lane & 15;
    int ndg = min(nd0 + ndl, rend - 1);
    uint4 pv = pk4[ndg * 16 + c4];
    int r0 = 2 * ndl;
    *(uint2*)&lx[r0 * 136 + c4 * 4] =
        make_uint2((pv.x & 0xffffu) | (pv.y << 16), (pv.z & 0xffffu) | (pv.w << 16));
    *(uint2*)&lx[(r0 + 1) * 136 + c4 * 4] =
        make_uint2((pv.x >> 16) | (pv.y & 0xffff0000u), (pv.z >> 16) | (pv.w & 0xffff0000u));
  }
  // gather 2 nodes (independent short chains; 16-lane groups x uint4 loads)
#pragma unroll
  for (int sub = 0; sub < 2; ++sub) {
    int ndl = 2 * w + sub;
    int n = nd0 + ndl;
    if (n >= rend) break;
    int s = row_off[n], en = row_off[n + 1];
    float a0x = 0.f, a0y = 0.f, a0z = 0.f, a0w = 0.f;
    float a1x = 0.f, a1y = 0.f, a1z = 0.f, a1w = 0.f;
    for (int e = s; e < en; e += 8) {
#pragma unroll
      for (int h = 0; h < 2; ++h) {
        int ee = e + h * 4 + g;
        int idx = sorted_src[min(ee, en - 1)];
        uint4 wv = pk4[idx * 16 + col];
        if (ee >= en) { wv.x = 0u; wv.y = 0u; wv.z = 0u; wv.w = 0u; }
        a0x += lo16(wv.x); a1x += hi16(wv.x);
        a0y += lo16(wv.y); a1y += hi16(wv.y);
        a0z += lo16(wv.z); a1z += hi16(wv.z);
        a0w += lo16(wv.w); a1w += hi16(wv.w);
      }
    }
    a0x += __shfl_xor(a0x, 16); a0x += __shfl_xor(a0x, 32);
    a0y += __shfl_xor(a0y, 16); a0y += __shfl_xor(a0y, 32);
    a0z += __shfl_xor(a0z, 16); a0z += __shfl_xor(a0z, 32);
    a0w += __shfl_xor(a0w, 16); a0w += __shfl_xor(a0w, 32);
    a1x += __shfl_xor(a1x, 16); a1x += __shfl_xor(a1x, 32);
    a1y += __shfl_xor(a1y, 16); a1y += __shfl_xor(a1y, 32);
    a1z += __shfl_xor(a1z, 16); a1z += __shfl_xor(a1z, 32);
    a1w += __shfl_xor(a1w, 16); a1w += __shfl_xor(a1w, 32);
    if (g == 0) {
      int r0 = 2 * ndl;
      *(uint2*)&lx[r0 * 136 + 64 + col * 4] =
          make_uint2(f2b(a0x) | (f2b(a0y) << 16), f2b(a0z) | (f2b(a0w) << 16));
      *(uint2*)&lx[(r0 + 1) * 136 + 64 + col * 4] =
          make_uint2(f2b(a1x) | (f2b(a1y) << 16), f2b(a1z) | (f2b(a1w) << 16));
    }
  }
  __syncthreads();           // the ONLY barrier: all 4 waves participate
  if (w != 0) return;        // waves 1-3 done; wave 0 runs the update tile

  // --- phase 2 (wave 0 only; no barriers needed) ---
  int f32 = dflag[0];
  int q = g, l15 = col;
  const unsigned short* wm = wt;            // msg^T  [64][64]  (row = out col)
  const unsigned short* wg = wt + 4096;     // gate^T [64][128]
  const unsigned short* wc = wt + 12288;    // cand^T [64][128]

  // msg phase: C[16x64] = agg[16x64] @ W_msg[64x64]
  short8_t a0 = *(const short8_t*)&lx[l15 * 136 + 64 + q * 8];
  short8_t a1 = *(const short8_t*)&lx[l15 * 136 + 96 + q * 8];
  f32x4_t msgc[4];
#pragma unroll
  for (int ct = 0; ct < 4; ++ct) {
    f32x4_t acc = {0.f, 0.f, 0.f, 0.f};
    short8_t b0 = *(const short8_t*)&wm[(ct * 16 + l15) * 64 + q * 8];
    short8_t b1 = *(const short8_t*)&wm[(ct * 16 + l15) * 64 + 32 + q * 8];
    acc = __builtin_amdgcn_mfma_f32_16x16x32_bf16(a0, b0, acc, 0, 0, 0);
    acc = __builtin_amdgcn_mfma_f32_16x16x32_bf16(a1, b1, acc, 0, 0, 0);
    msgc[ct] = acc;
  }
  // combined = msg + inject -> back into cols 64-127
  int nA = nd0 + q * 2, nB = nA + 1;
  int flA = (nA < rend) ? flags[nA] : 0;
  int flB = (nB < rend) ? flags[nB] : 0;
#pragma unroll
  for (int ct = 0; ct < 4; ++ct) {
    int c2 = ct * 16 + l15;
    float pj0 = projected[c2], pj1 = projected[64 + c2];
#pragma unroll
    for (int r = 0; r < 4; ++r) {
      int row = q * 4 + r;
      int fl = (r < 2) ? flA : flB;
      float inj = fl ? ((row & 1) ? pj1 : pj0) : 0.f;
      lx[row * 136 + 64 + c2] = (unsigned short)f2b(msgc[ct][r] + inj);
    }
  }

  // gate/cand phase: K=128 over [state | combined]
  short8_t xa[4];
#pragma unroll
  for (int ks = 0; ks < 4; ++ks)
    xa[ks] = *(const short8_t*)&lx[l15 * 136 + ks * 32 + q * 8];
  // prev-state to regs BEFORE result staging overwrites the strip
  float ps[16];
#pragma unroll
  for (int ct = 0; ct < 4; ++ct)
#pragma unroll
    for (int rp = 0; rp < 2; ++rp) {
      int row = q * 4 + 2 * rp;
      ps[ct * 4 + rp * 2 + 0] = b2f(lx[row * 136 + ct * 16 + l15]);
      ps[ct * 4 + rp * 2 + 1] = b2f(lx[(row + 1) * 136 + ct * 16 + l15]);
    }
  // result staging: strip reused as [16 rows][64] f32 (4 KB; row = ndl*2+p)
  float* soutw = (float*)lx4;
#pragma unroll
  for (int ct = 0; ct < 4; ++ct) {
    f32x4_t accg = {0.f, 0.f, 0.f, 0.f}, accc = {0.f, 0.f, 0.f, 0.f};
#pragma unroll
    for (int ks = 0; ks < 4; ++ks) {
      short8_t bg = *(const short8_t*)&wg[(ct * 16 + l15) * 128 + ks * 32 + q * 8];
      short8_t bc = *(const short8_t*)&wc[(ct * 16 + l15) * 128 + ks * 32 + q * 8];
      accg = __builtin_amdgcn_mfma_f32_16x16x32_bf16(xa[ks], bg, accg, 0, 0, 0);
      accc = __builtin_amdgcn_mfma_f32_16x16x32_bf16(xa[ks], bc, accc, 0, 0, 0);
    }
    int c2 = ct * 16 + l15;
    float bgv = ldf(b_gate, c2, f32), bcv = ldf(b_cand, c2, f32);
#pragma unroll
    for (int rp = 0; rp < 2; ++rp) {
      int r = q * 4 + 2 * rp;   // strip row (batch0); r+1 = batch1
      float z0 = fsig(accg[2 * rp] + bgv);
      float c0 = ftanh(accc[2 * rp] + bcv);
      soutw[r * 64 + c2] = (1.f - z0) * ps[ct * 4 + rp * 2 + 0] + z0 * c0;
      float z1 = fsig(accg[2 * rp + 1] + bgv);
      float c1 = ftanh(accc[2 * rp + 1] + bcv);
      soutw[(r + 1) * 64 + c2] = (1.f - z1) * ps[ct * 4 + rp * 2 + 1] + z1 * c1;
    }
  }

  int nlim = min(8, rend - nd0);
  // eff-membership scan (4 entries/lane; single-wave LDS atomics)
  for (int i = lane; i < kEff; i += 64) {
    unsigned rel = (unsigned)(eff_idx[i] - nd0);
    if (rel < (unsigned)nlim) { int s = atomicAdd(&smcnt, 1); smatch[s] = (int)rel; }
  }

  // wave-contiguous aligned copy-out (16B-aligned bases; 2 KB/plane)
  int nvalid = nlim * 64;
  if (f32) {
    float* po = (float*)out + kOutOff;
#pragma unroll
    for (int p = 0; p < 2; ++p)
      for (int j = lane * 4; j < nvalid; j += 256) {
        int ndl = j >> 6, c = j & 63;
        float4 v = *(float4*)((char*)lx4 + ((ndl * 2 + p) * 64 + c) * 4);
        *(float4*)(po + p * kNH + nd0 * 64 + j) = v;
      }
  } else {
    unsigned short* po = (unsigned short*)out + kOutOff;
#pragma unroll
    for (int p = 0; p < 2; ++p)
      for (int j = lane * 8; j < nvalid; j += 512) {
        int ndl = j >> 6, c = j & 63;
        const char* base = (const char*)lx4 + ((ndl * 2 + p) * 64 + c) * 4;
        float4 v0 = *(const float4*)base;
        float4 v1 = *(const float4*)(base + 16);
        uint4 o;
        o.x = f2b(v0.x) | (f2b(v0.y) << 16);
        o.y = f2b(v0.z) | (f2b(v0.w) << 16);
        o.z = f2b(v1.x) | (f2b(v1.y) << 16);
        o.w = f2b(v1.z) | (f2b(v1.w) << 16);
        *(uint4*)(po + p * kNH + nd0 * 64 + j) = o;
      }
  }

  // eff accumulation: register pre-sum, then 2 atomics/lane to range slice
  int cnt = smcnt;
  if (cnt) {
    float a0s = 0.f, a1s = 0.f;
    const float* sf = (const float*)lx4;
    for (int m = 0; m < cnt; ++m) {
      int rel = smatch[m];
      float v0 = sf[(rel * 2 + 0) * 64 + lane];
      float v1 = sf[(rel * 2 + 1) * 64 + lane];
      if (!f32) { v0 = b2f((unsigned short)f2b(v0)); v1 = b2f((unsigned short)f2b(v1)); }
      a0s += v0; a1s += v1;
    }
    atomicAdd(&eff_acc[x * 128 + lane], a0s);        // device-scope, no fence
    atomicAdd(&eff_acc[x * 128 + 64 + lane], a1s);
  }
}

// --- readout: tiny decode + policy heads from per-range eff_acc slices ------
// Kernel boundary provides cross-XCD visibility of k_gupd's eff_acc atomics
// (one command-processor flush instead of per-block fences — round 10).
extern "C" __global__ void k_readout(const void* __restrict__ W_dec,
                                     const void* __restrict__ b_dec,
                                     const void* __restrict__ W_mean,
                                     const void* __restrict__ b_mean,
                                     const void* __restrict__ W_ls,
                                     const void* __restrict__ b_ls,
                                     const float* __restrict__ eff_acc,
                                     const int* __restrict__ dflag,
                                     void* __restrict__ out) {
  __shared__ float ro[128], dec[128];
  int f32 = dflag[0];
  int t = threadIdx.x;            // 128 threads
  if (t < 128) {
    float s = 0.f;
#pragma unroll
    for (int r = 0; r < kRanges; ++r) s += eff_acc[r * 128 + t];
    ro[t] = s * (1.f / kEff);
  }
  __syncthreads();
  if (t < 128) {
    int bb = t >> 6, h = t & 63;
    float d = ldf(b_dec, h, f32);
    for (int k = 0; k < 64; ++k) d += ro[bb * 64 + k] * ldf(W_dec, k * 64 + h, f32);
    dec[t] = tanhf(d);
  }
  __syncthreads();
  if (t < kB * kA) {
    int bb = t / kA, a = t % kA;
    float m = ldf(b_mean, a, f32), l = ldf(b_ls, a, f32);
    for (int k = 0; k < 64; ++k) {
      float dv = dec[bb * 64 + k];
      m += dv * ldf(W_mean, k * kA + a, f32);
      l += dv * ldf(W_ls, k * kA + a, f32);
    }
    l = fminf(fmaxf(l, -5.f), 2.f);
    stf(out, t, m, f32);            // mean[2][18]
    stf(out, kB * kA + t, l, f32);  // log_std[2][18]
  }
}

extern "C" void kernel_launch(void* const* d_in, const int* in_sizes, int n_in,
                              void* d_out, int out_size, void* d_ws, size_t ws_size,
                              hipStream_t stream) {
  (void)in_sizes; (void)n_in; (void)out_size; (void)ws_size;
  const void* obs    = d_in[0];
  const void* state  = d_in[1];
  const void* W_in   = d_in[2];
  const void* b_in   = d_in[3];
  const void* W_msg  = d_in[4];
  const void* W_gate = d_in[5];
  const void* b_gate = d_in[6];
  const void* W_cand = d_in[7];
  const void* b_cand = d_in[8];
  const void* W_dec  = d_in[9];
  const void* b_dec  = d_in[10];
  const void* W_mean = d_in[11];
  const void* b_mean = d_in[12];
  const void* W_ls   = d_in[13];
  const void* b_ls   = d_in[14];
  const int* src = (const int*)d_in[15];
  const int* dst = (const int*)d_in[16];
  const int* aff = (const int*)d_in[17];
  const int* eff = (const int*)d_in[18];

  // workspace layout (~30 MB; agg eliminated by the fusion)
  int* wsp        = (int*)d_ws;
  int* flags      = wsp;                    // [N]     (zeroed by k_prep b0)
  int* deg_c      = flags + kN;             // [kChunks*N]; becomes chunk_base in scan3
  int* row_off    = deg_c + kChunks * kN;   // [N+1] -> pad N+64
  int* partials   = row_off + (kN + 64);    // [512]
  int* dflag      = partials + 512;         // [16]
  float* projected = (float*)(dflag + 16);           // [128]
  float* eff_acc   = projected + 128;                // [8*128] (zeroed by prep b0)
  int* sorted_src  = (int*)(eff_acc + 1024);         // [E]
  unsigned int* pk  = (unsigned int*)(sorted_src + kE);  // [N*H]
  unsigned short* wt = (unsigned short*)(pk + kNH);      // [20480] bf16

  k_prep<<<1 + kHistB + kWprepBlocks, 1024, 0, stream>>>(
      (const unsigned short*)W_cand, obs, W_in, b_in, aff, dst,
      W_msg, W_gate, W_cand, dflag, flags, projected, deg_c, wt, eff_acc);
  k_scan1<<<kScanB, 256, 0, stream>>>(deg_c, row_off, partials);
  k_scan3<<<kScanB, 256, 0, stream>>>(row_off, partials, deg_c);
  k_scatter<<<kHistB + kPackBlocks, 1024, 0, stream>>>(
      src, dst, deg_c, sorted_src, (const unsigned short*)W_cand, state, pk);
  k_gupd<<<kGuB, 256, 0, stream>>>(pk, row_off, sorted_src, wt, b_gate, b_cand,
                                   flags, projected, dflag, d_out, eff, eff_acc);
  k_readout<<<1, 128, 0, stream>>>(W_dec, b_dec, W_mean, b_mean, W_ls, b_ls,
                                   eff_acc, dflag, d_out);
}

// Round 16
// 248.147 us; speedup vs baseline: 1.0927x; 1.0224x over previous
//
#include <hip/hip_runtime.h>
#include <hip/hip_bf16.h>

// Problem constants (WholeBrainRateModel)
constexpr int kN   = 50000;    // nodes
constexpr int kH   = 64;       // hidden
constexpr int kB   = 2;        // batch
constexpr int kE   = 1000000;  // edges
constexpr int kObs = 128;
constexpr int kA   = 18;
constexpr int kAff = 512;
constexpr int kEff = 256;
constexpr int kNH  = kN * kH;
constexpr int kOutOff = 2 * kB * kA;  // 72 elements: mean+log_std before next_state
constexpr int kRanges = 8;                // node ranges (bid&7 -> XCD heuristic)
constexpr int kNr  = kN / kRanges;        // 6250 nodes per range (25 KB LDS)
constexpr int kChunks = 64;               // edge chunks
constexpr int kEc  = kE / kChunks;        // 15625 edges per chunk
constexpr int kHistB = kRanges * kChunks; // 512 hist/scatter blocks (1024 thr)
constexpr int kPackPerR = (kNr + 127) / 128;      // 49 pack blocks per range
constexpr int kPackBlocks = kRanges * kPackPerR;  // 392 (range-aligned)
constexpr int kWprepBlocks = 20;                  // 20480 / 1024
constexpr int kScanB = (kN + 255) / 256;          // 196 (1 node/thread)
constexpr int kGuPerR = (kNr + 7) / 8;            // 782 fused blocks per range
constexpr int kGuB = kRanges * kGuPerR;           // 6256 (8 nodes/block)

typedef __attribute__((ext_vector_type(8))) short short8_t;  // 8 bf16 (4 VGPRs)
typedef __attribute__((ext_vector_type(4))) float f32x4_t;

// dtype-adaptive load/store (flag==1 -> float32 buffers, else bf16).
__device__ __forceinline__ float ldf(const void* p, int i, int f32) {
  if (f32) return ((const float*)p)[i];
  unsigned short u = ((const unsigned short*)p)[i];
  union { unsigned int x; float f; } v; v.x = ((unsigned int)u) << 16; return v.f;
}
__device__ __forceinline__ void stf(void* p, int i, float val, int f32) {
  if (f32) ((float*)p)[i] = val;
  else ((__hip_bfloat16*)p)[i] = __float2bfloat16(val);
}
__device__ __forceinline__ float lo16(unsigned int w) {
  union { unsigned int i; float f; } v; v.i = w << 16; return v.f;
}
__device__ __forceinline__ float hi16(unsigned int w) {
  union { unsigned int i; float f; } v; v.i = w & 0xffff0000u; return v.f;
}
__device__ __forceinline__ float b2f(unsigned short u) {
  union { unsigned int i; float f; } v; v.i = ((unsigned int)u) << 16; return v.f;
}
__device__ __forceinline__ unsigned int f2b(float f) {  // rne bf16 bits
  union { float f; unsigned int u; } v; v.f = f;
  unsigned int r = v.u + 0x7fffu + ((v.u >> 16) & 1u);
  return r >> 16;
}
// fast transcendentals: v_exp_f32 + v_rcp_f32; error ~1e-6 rel, far below the
// bf16 rounding already present in the pipeline (absmax budget ~2e-3).
__device__ __forceinline__ float fsig(float x) {
  return __builtin_amdgcn_rcpf(1.f + __expf(-x));
}
__device__ __forceinline__ float ftanh(float x) {
  return 1.f - 2.f * __builtin_amdgcn_rcpf(__expf(2.f * x) + 1.f);
}
// wave-0 dtype detector (identical data in every block -> identical answer)
__device__ __forceinline__ int detect64(const unsigned short* wprobe, int t) {
  int hits = 0;
  for (int k = 0; k < 4; ++k) {
    unsigned short u = wprobe[(t * 4 + k) * 2];
    int e = (u >> 7) & 0xFF;
    if ((u & 0x7FFFu) != 0 && e >= 108 && e <= 128) hits++;
  }
  for (int off = 32; off; off >>= 1) hits += __shfl_down(hits, off);
  return (hits < 128) ? 1 : 0;  // few plausible-bf16 => f32
}

// --- fused prep (1024 thr): b0 = detect+flags+proj; b1..512 = hist; wprep ---
// Histogram with ZERO global atomics (rounds 3/4: every global atomic costs a
// ~32 B EA write packet; 1M of them = ~32 MB + 45+ us). Round 5 lesson: keep
// >=2 blk/CU and short per-thread loops. Block (r,c) LDS-counts chunk c's
// edges landing in range r, then plain coalesced stores to deg_c[c][range r].
extern "C" __global__ __launch_bounds__(1024) void k_prep(
    const unsigned short* __restrict__ wprobe,
    const void* __restrict__ obs,
    const void* __restrict__ W_in,
    const void* __restrict__ b_in,
    const int* __restrict__ aff_idx,
    const int* __restrict__ dst,
    const void* __restrict__ W_msg,
    const void* __restrict__ W_gate,
    const void* __restrict__ W_cand,
    int* __restrict__ dflag,
    int* __restrict__ flags,
    float* __restrict__ projected,
    int* __restrict__ deg_c,
    unsigned short* __restrict__ wt,
    float* __restrict__ eff_acc) {
  __shared__ int sdeg[kNr];
  int t = threadIdx.x, b = blockIdx.x;
  if (b == 0) {
    __shared__ int sflag;
    if (t < 64) { int f = detect64(wprobe, t); if (t == 0) { sflag = f; dflag[0] = f; } }
    for (int i = t; i < kN; i += 1024) flags[i] = 0;
    eff_acc[t] = 0.f;                      // 8 range slices x 128
    __syncthreads();
    int f32 = sflag;
    if (t < kAff) flags[aff_idx[t]] = 1;
    if (t < kB * kH) {
      int bb = t >> 6, h = t & 63;
      float acc = ldf(b_in, h, f32);
      for (int o = 0; o < kObs; ++o)
        acc += ldf(obs, bb * kObs + o, f32) * ldf(W_in, o * kH + h, f32);
      projected[t] = acc;
    }
  } else if (b <= kHistB) {
    int h = b - 1, r = h & 7, c = h >> 3;
    int r0 = r * kNr;
    for (int i = t; i < kNr; i += 1024) sdeg[i] = 0;
    __syncthreads();
    int end = (c + 1) * kEc;
    for (int e = c * kEc + t; e < end; e += 1024) {
      unsigned rel = (unsigned)(dst[e] - r0);
      if (rel < (unsigned)kNr) atomicAdd(&sdeg[rel], 1);  // LDS atomic only
    }
    __syncthreads();
    for (int i = t; i < kNr; i += 1024) deg_c[c * kN + r0 + i] = sdeg[i];
  } else {
    __shared__ int sflag;
    if (t < 64) { int f = detect64(wprobe, t); if (t == 0) sflag = f; }
    __syncthreads();
    int f32 = sflag;
    int i = (b - 1 - kHistB) * 1024 + t;  // 0..20479
    if (i < 4096) {
      int n = i >> 6, k = i & 63;
      wt[i] = (unsigned short)f2b(ldf(W_msg, k * 64 + n, f32));
    } else if (i < 12288) {
      int j = i - 4096; int n = j >> 7, k = j & 127;
      wt[i] = (unsigned short)f2b(ldf(W_gate, k * 64 + n, f32));
    } else if (i < 20480) {
      int j = i - 12288; int n = j >> 7, k = j & 127;
      wt[i] = (unsigned short)f2b(ldf(W_cand, k * 64 + n, f32));
    }
  }
}

// --- scan: 196 blocks x 256 thr, 1 node/thread ------------------------------
extern "C" __global__ void k_scan1(const int* __restrict__ deg_c,
                                   int* __restrict__ row_off,
                                   int* __restrict__ partials) {
  __shared__ int sd[256];
  int t = threadIdx.x;
  int n = blockIdx.x * 256 + t;
  int s = 0;
  if (n < kN) {
    for (int c = 0; c < kChunks; ++c) s += deg_c[c * kN + n];
  }
  sd[t] = s;
  __syncthreads();
  for (int off = 1; off < 256; off <<= 1) {
    int v = (t >= off) ? sd[t - off] : 0;
    __syncthreads();
    sd[t] += v;
    __syncthreads();
  }
  int excl = sd[t] - s;
  if (t == 255) partials[blockIdx.x] = sd[255];
  if (n < kN) row_off[n] = excl;
}

// scan2 folded in; additionally transforms deg_c in place into
// chunk_base[c][n] = row_off[n] + sum_{c'<c} deg_c[c'][n]  (atomic-free
// scatter positions). Each node column is owned by exactly one thread.
extern "C" __global__ void k_scan3(int* __restrict__ row_off,
                                   const int* __restrict__ partials,
                                   int* __restrict__ deg_c) {
  __shared__ int sd[256];
  int t = threadIdx.x;
  int s = 0;
  for (int j = t; j < (int)blockIdx.x; j += 256) s += partials[j];
  sd[t] = s;
  __syncthreads();
  for (int off = 128; off; off >>= 1) {
    if (t < off) sd[t] += sd[t + off];
    __syncthreads();
  }
  int base = sd[0];
  int n = blockIdx.x * 256 + t;
  if (n < kN) {
    int v = row_off[n] + base;
    row_off[n] = v;
    int run = v;
#pragma unroll 8
    for (int c = 0; c < kChunks; ++c) {
      int d = deg_c[c * kN + n];
      deg_c[c * kN + n] = run;   // in-place: deg -> chunk_base
      run += d;
    }
  }
  if (blockIdx.x == 0 && t == 0) row_off[kN] = kE;
}

// --- scatter (+pack riding along), 1024 thr: ZERO global atomics ------------
// Block (r,c): load range r's chunk_base slice into an LDS cursor, then for
// chunk c's in-range edges take slots via LDS atomicAdd and store. Slots are
// disjoint across chunks by construction (chunk_base prefix). bid&7 = r keeps
// each range's ~500 KB sorted_src window written by one XCD (L2 locality).
// Pack blocks (bid >= 512): range-aligned: pack block p handles nodes of
// range p&7 -> pk's range-r lines are written by XCD r's L2.
extern "C" __global__ __launch_bounds__(1024) void k_scatter(
    const int* __restrict__ src,
    const int* __restrict__ dst,
    const int* __restrict__ chunk_base,
    int* __restrict__ sorted_src,
    const unsigned short* __restrict__ wprobe,
    const void* __restrict__ state,
    unsigned int* __restrict__ pack) {
  __shared__ int scur[kNr];
  int t = threadIdx.x;
  if (blockIdx.x < kHistB) {
    int r = blockIdx.x & 7, c = blockIdx.x >> 3;
    int r0 = r * kNr;
    for (int i = t; i < kNr; i += 1024) scur[i] = chunk_base[c * kN + r0 + i];
    __syncthreads();
    int end = (c + 1) * kEc;
    for (int e = c * kEc + t; e < end; e += 1024) {
      unsigned rel = (unsigned)(dst[e] - r0);
      if (rel < (unsigned)kNr) {
        int pos = atomicAdd(&scur[rel], 1);   // LDS atomic only
        sorted_src[pos] = src[e];
      }
    }
  } else {
    __shared__ int sflag;
    if (t < 64) { int f = detect64(wprobe, t); if (t == 0) sflag = f; }
    __syncthreads();
    int f32 = sflag;
    int p = blockIdx.x - kHistB;           // kHistB = 512 (div by 8): XCD = p&7
    int x = p & 7, j = p >> 3;
    int nb = x * kNr + j * 128;            // first node of this pack block
    int nl = min(nb + 128, (x + 1) * kNr); // range-local node limit
    int i = nb * 64 + t * 8;               // 8 elems/thread
    if (i < nl * 64) {
      uint4 o0, o1;
      if (!f32) {
        // bf16 inputs: pack is a pure bit-interleave (no rounding round-trip)
        uint4 a = *(const uint4*)((const unsigned short*)state + i);
        uint4 c4 = *(const uint4*)((const unsigned short*)state + kNH + i);
        o0.x = (a.x & 0xffffu) | (c4.x << 16);
        o0.y = (a.x >> 16)     | (c4.x & 0xffff0000u);
        o0.z = (a.y & 0xffffu) | (c4.y << 16);
        o0.w = (a.y >> 16)     | (c4.y & 0xffff0000u);
        o1.x = (a.z & 0xffffu) | (c4.z << 16);
        o1.y = (a.z >> 16)     | (c4.z & 0xffff0000u);
        o1.z = (a.w & 0xffffu) | (c4.w << 16);
        o1.w = (a.w >> 16)     | (c4.w & 0xffff0000u);
      } else {
        const float* sf = (const float*)state;
        unsigned int w[8];
#pragma unroll
        for (int k = 0; k < 8; ++k)
          w[k] = f2b(sf[i + k]) | (f2b(sf[kNH + i + k]) << 16);
        o0 = make_uint4(w[0], w[1], w[2], w[3]);
        o1 = make_uint4(w[4], w[5], w[6], w[7]);
      }
      *(uint4*)&pack[i] = o0;
      *(uint4*)&pack[i + 4] = o1;
    }
  }
}

// --- FUSED gather+update v2 (round 16): ALL 4 waves alive end-to-end --------
// Round-15's fusion left occupancy at 33% because waves 1-3 exited after the
// gather barrier (if(w)return), halving resident TLP during the latency-bound
// random-gather phase. v2: the update tile is split BY COLUMN-BLOCK — wave w
// owns output cols [16w,16w+16) (ct = w) — so all 4 waves gather (2 nodes
// each, high TLP) AND update. Hazards isolated via separate LDS areas:
// comb[16][68] bf16 (combined; doesn't overwrite agg cols -> no extra
// barrier before the a-reads) and sres[16][64] f32 (results; doesn't overlay
// the strip). 3 cheap 4-wave barriers. agg buffer still eliminated.
extern "C" __global__ __launch_bounds__(256) void k_gupd(
    const unsigned int* __restrict__ pack,
    const int* __restrict__ row_off,     // span = [off[n], off[n+1])
    const int* __restrict__ sorted_src,
    const unsigned short* __restrict__ wt,   // prepped bf16 Wt msg|gate|cand
    const void* __restrict__ b_gate,
    const void* __restrict__ b_cand,
    const int* __restrict__ flags,
    const float* __restrict__ projected,
    const int* __restrict__ dflag,
    void* __restrict__ out,
    const int* __restrict__ eff_idx,
    float* __restrict__ eff_acc) {
  __shared__ uint4 lx4[274];           // 4384 B: strip [16 rows][136 u16]
  __shared__ unsigned short comb[16 * 68];  // 2176 B: combined bf16 [16][68]
  __shared__ float sres[16 * 64];      // 4096 B: results f32 [16][64]
  __shared__ int smatch[256];
  __shared__ int smcnt;
  unsigned short* lx = (unsigned short*)lx4;
  int t = threadIdx.x;
  int w = t >> 6, lane = t & 63;
  int g = lane >> 4, col = lane & 15;
  int x = blockIdx.x & 7, jb = blockIdx.x >> 3;
  int nd0 = x * kNr + jb * 8;    // block's first node (8 nodes)
  int rend = (x + 1) * kNr;      // range-local node limit
  if (nd0 >= rend) return;
  if (t == 0) smcnt = 0;

  const uint4* pk4 = (const uint4*)pack;

  // --- phase 1 (all 4 waves): stage state + gather own 2 nodes into strip ---
  if (lane < 32) {
    int ndl = 2 * w + (lane >> 4), c4 = lane & 15;
    int ndg = min(nd0 + ndl, rend - 1);
    uint4 pv = pk4[ndg * 16 + c4];
    int r0 = 2 * ndl;
    *(uint2*)&lx[r0 * 136 + c4 * 4] =
        make_uint2((pv.x & 0xffffu) | (pv.y << 16), (pv.z & 0xffffu) | (pv.w << 16));
    *(uint2*)&lx[(r0 + 1) * 136 + c4 * 4] =
        make_uint2((pv.x >> 16) | (pv.y & 0xffff0000u), (pv.z >> 16) | (pv.w & 0xffff0000u));
  }
#pragma unroll
  for (int sub = 0; sub < 2; ++sub) {
    int ndl = 2 * w + sub;
    int n = nd0 + ndl;
    if (n >= rend) break;
    int s = row_off[n], en = row_off[n + 1];
    float a0x = 0.f, a0y = 0.f, a0z = 0.f, a0w = 0.f;
    float a1x = 0.f, a1y = 0.f, a1z = 0.f, a1w = 0.f;
    for (int e = s; e < en; e += 8) {
#pragma unroll
      for (int h = 0; h < 2; ++h) {
        int ee = e + h * 4 + g;
        int idx = sorted_src[min(ee, en - 1)];
        uint4 wv = pk4[idx * 16 + col];
        if (ee >= en) { wv.x = 0u; wv.y = 0u; wv.z = 0u; wv.w = 0u; }
        a0x += lo16(wv.x); a1x += hi16(wv.x);
        a0y += lo16(wv.y); a1y += hi16(wv.y);
        a0z += lo16(wv.z); a1z += hi16(wv.z);
        a0w += lo16(wv.w); a1w += hi16(wv.w);
      }
    }
    a0x += __shfl_xor(a0x, 16); a0x += __shfl_xor(a0x, 32);
    a0y += __shfl_xor(a0y, 16); a0y += __shfl_xor(a0y, 32);
    a0z += __shfl_xor(a0z, 16); a0z += __shfl_xor(a0z, 32);
    a0w += __shfl_xor(a0w, 16); a0w += __shfl_xor(a0w, 32);
    a1x += __shfl_xor(a1x, 16); a1x += __shfl_xor(a1x, 32);
    a1y += __shfl_xor(a1y, 16); a1y += __shfl_xor(a1y, 32);
    a1z += __shfl_xor(a1z, 16); a1z += __shfl_xor(a1z, 32);
    a1w += __shfl_xor(a1w, 16); a1w += __shfl_xor(a1w, 32);
    if (g == 0) {
      int r0 = 2 * ndl;
      *(uint2*)&lx[r0 * 136 + 64 + col * 4] =
          make_uint2(f2b(a0x) | (f2b(a0y) << 16), f2b(a0z) | (f2b(a0w) << 16));
      *(uint2*)&lx[(r0 + 1) * 136 + 64 + col * 4] =
          make_uint2(f2b(a1x) | (f2b(a1y) << 16), f2b(a1z) | (f2b(a1w) << 16));
    }
  }
  __syncthreads();   // barrier A: strip (state + agg) complete

  // --- phase 2 (all 4 waves): msg MFMA for ct = w; combined -> comb ---
  int f32 = dflag[0];
  int q = g, l15 = col;
  const unsigned short* wm = wt;            // msg^T  [64][64]  (row = out col)
  const unsigned short* wg = wt + 4096;     // gate^T [64][128]
  const unsigned short* wc = wt + 12288;    // cand^T [64][128]

  short8_t a0 = *(const short8_t*)&lx[l15 * 136 + 64 + q * 8];
  short8_t a1 = *(const short8_t*)&lx[l15 * 136 + 96 + q * 8];
  f32x4_t macc = {0.f, 0.f, 0.f, 0.f};
  {
    short8_t b0 = *(const short8_t*)&wm[(w * 16 + l15) * 64 + q * 8];
    short8_t b1 = *(const short8_t*)&wm[(w * 16 + l15) * 64 + 32 + q * 8];
    macc = __builtin_amdgcn_mfma_f32_16x16x32_bf16(a0, b0, macc, 0, 0, 0);
    macc = __builtin_amdgcn_mfma_f32_16x16x32_bf16(a1, b1, macc, 0, 0, 0);
  }
  int nA = nd0 + q * 2, nB = nA + 1;
  int flA = (nA < rend) ? flags[nA] : 0;
  int flB = (nB < rend) ? flags[nB] : 0;
  {
    int c2 = w * 16 + l15;
    float pj0 = projected[c2], pj1 = projected[64 + c2];
#pragma unroll
    for (int r = 0; r < 4; ++r) {
      int row = q * 4 + r;
      int fl = (r < 2) ? flA : flB;
      float inj = fl ? ((row & 1) ? pj1 : pj0) : 0.f;
      comb[row * 68 + c2] = (unsigned short)f2b(macc[r] + inj);
    }
  }
  __syncthreads();   // barrier B: comb complete

  // --- phase 3 (all 4 waves): gate/cand for ct = w -> sres ---
  short8_t xa[4];
#pragma unroll
  for (int ks = 0; ks < 2; ++ks)      // K 0..63 from state (strip cols 0-63)
    xa[ks] = *(const short8_t*)&lx[l15 * 136 + ks * 32 + q * 8];
#pragma unroll
  for (int ks = 0; ks < 2; ++ks)      // K 64..127 from comb
    xa[2 + ks] = *(const short8_t*)&comb[l15 * 68 + ks * 32 + q * 8];
  // prev-state for own col block (strip cols untouched -> safe to read here)
  float ps[4];
#pragma unroll
  for (int rp = 0; rp < 2; ++rp) {
    int row = q * 4 + 2 * rp;
    ps[rp * 2 + 0] = b2f(lx[row * 136 + w * 16 + l15]);
    ps[rp * 2 + 1] = b2f(lx[(row + 1) * 136 + w * 16 + l15]);
  }
  {
    f32x4_t accg = {0.f, 0.f, 0.f, 0.f}, accc = {0.f, 0.f, 0.f, 0.f};
#pragma unroll
    for (int ks = 0; ks < 4; ++ks) {
      short8_t bg = *(const short8_t*)&wg[(w * 16 + l15) * 128 + ks * 32 + q * 8];
      short8_t bc = *(const short8_t*)&wc[(w * 16 + l15) * 128 + ks * 32 + q * 8];
      accg = __builtin_amdgcn_mfma_f32_16x16x32_bf16(xa[ks], bg, accg, 0, 0, 0);
      accc = __builtin_amdgcn_mfma_f32_16x16x32_bf16(xa[ks], bc, accc, 0, 0, 0);
    }
    int c2 = w * 16 + l15;
    float bgv = ldf(b_gate, c2, f32), bcv = ldf(b_cand, c2, f32);
#pragma unroll
    for (int rp = 0; rp < 2; ++rp) {
      int r = q * 4 + 2 * rp;   // strip row (batch0); r+1 = batch1
      float z0 = fsig(accg[2 * rp] + bgv);
      float c0 = ftanh(accc[2 * rp] + bcv);
      sres[r * 64 + c2] = (1.f - z0) * ps[rp * 2 + 0] + z0 * c0;
      float z1 = fsig(accg[2 * rp + 1] + bgv);
      float c1 = ftanh(accc[2 * rp + 1] + bcv);
      sres[(r + 1) * 64 + c2] = (1.f - z1) * ps[rp * 2 + 1] + z1 * c1;
    }
  }
  // eff-membership scan (1 entry/thread, L2-hot) before the last barrier
  int nlim = min(8, rend - nd0);
  if (t < kEff) {
    unsigned rel = (unsigned)(eff_idx[t] - nd0);
    if (rel < (unsigned)nlim) { int s = atomicAdd(&smcnt, 1); smatch[s] = (int)rel; }
  }
  __syncthreads();   // barrier C: sres + smatch complete

  // --- phase 4 (all 4 waves): block-linear aligned copy-out + eff tail ---
  int nvalid = nlim * 64;
  if (f32) {
    float* po = (float*)out + kOutOff;
#pragma unroll
    for (int p = 0; p < 2; ++p)
      for (int j = t * 4; j < nvalid; j += 1024) {
        int ndl = j >> 6, c = j & 63;
        float4 v = *(float4*)&sres[(ndl * 2 + p) * 64 + c];
        *(float4*)(po + p * kNH + nd0 * 64 + j) = v;
      }
  } else {
    unsigned short* po = (unsigned short*)out + kOutOff;
#pragma unroll
    for (int p = 0; p < 2; ++p)
      for (int j = t * 8; j < nvalid; j += 2048) {
        int ndl = j >> 6, c = j & 63;
        const float* base = &sres[(ndl * 2 + p) * 64 + c];
        float4 v0 = *(const float4*)base;
        float4 v1 = *(const float4*)(base + 4);
        uint4 o;
        o.x = f2b(v0.x) | (f2b(v0.y) << 16);
        o.y = f2b(v0.z) | (f2b(v0.w) << 16);
        o.z = f2b(v1.x) | (f2b(v1.y) << 16);
        o.w = f2b(v1.z) | (f2b(v1.w) << 16);
        *(uint4*)(po + p * kNH + nd0 * 64 + j) = o;
      }
  }

  // eff accumulation: t<128 handles (p,c); per-range slice (contention /8)
  int cnt = smcnt;
  if (cnt && t < 128) {
    int p = t >> 6, c = t & 63;
    float s = 0.f;
    for (int m = 0; m < cnt; ++m) {
      int rel = smatch[m];
      float v = sres[(rel * 2 + p) * 64 + c];
      if (!f32) v = b2f((unsigned short)f2b(v));   // match stored precision
      s += v;
    }
    atomicAdd(&eff_acc[x * 128 + p * 64 + c], s);  // device-scope, no fence
  }
}

// --- readout: tiny decode + policy heads from per-range eff_acc slices ------
// Kernel boundary provides cross-XCD visibility of k_gupd's eff_acc atomics
// (one command-processor flush instead of per-block fences — round 10).
extern "C" __global__ void k_readout(const void* __restrict__ W_dec,
                                     const void* __restrict__ b_dec,
                                     const void* __restrict__ W_mean,
                                     const void* __restrict__ b_mean,
                                     const void* __restrict__ W_ls,
                                     const void* __restrict__ b_ls,
                                     const float* __restrict__ eff_acc,
                                     const int* __restrict__ dflag,
                                     void* __restrict__ out) {
  __shared__ float ro[128], dec[128];
  int f32 = dflag[0];
  int t = threadIdx.x;            // 128 threads
  if (t < 128) {
    float s = 0.f;
#pragma unroll
    for (int r = 0; r < kRanges; ++r) s += eff_acc[r * 128 + t];
    ro[t] = s * (1.f / kEff);
  }
  __syncthreads();
  if (t < 128) {
    int bb = t >> 6, h = t & 63;
    float d = ldf(b_dec, h, f32);
    for (int k = 0; k < 64; ++k) d += ro[bb * 64 + k] * ldf(W_dec, k * 64 + h, f32);
    dec[t] = tanhf(d);
  }
  __syncthreads();
  if (t < kB * kA) {
    int bb = t / kA, a = t % kA;
    float m = ldf(b_mean, a, f32), l = ldf(b_ls, a, f32);
    for (int k = 0; k < 64; ++k) {
      float dv = dec[bb * 64 + k];
      m += dv * ldf(W_mean, k * kA + a, f32);
      l += dv * ldf(W_ls, k * kA + a, f32);
    }
    l = fminf(fmaxf(l, -5.f), 2.f);
    stf(out, t, m, f32);            // mean[2][18]
    stf(out, kB * kA + t, l, f32);  // log_std[2][18]
  }
}

extern "C" void kernel_launch(void* const* d_in, const int* in_sizes, int n_in,
                              void* d_out, int out_size, void* d_ws, size_t ws_size,
                              hipStream_t stream) {
  (void)in_sizes; (void)n_in; (void)out_size; (void)ws_size;
  const void* obs    = d_in[0];
  const void* state  = d_in[1];
  const void* W_in   = d_in[2];
  const void* b_in   = d_in[3];
  const void* W_msg  = d_in[4];
  const void* W_gate = d_in[5];
  const void* b_gate = d_in[6];
  const void* W_cand = d_in[7];
  const void* b_cand = d_in[8];
  const void* W_dec  = d_in[9];
  const void* b_dec  = d_in[10];
  const void* W_mean = d_in[11];
  const void* b_mean = d_in[12];
  const void* W_ls   = d_in[13];
  const void* b_ls   = d_in[14];
  const int* src = (const int*)d_in[15];
  const int* dst = (const int*)d_in[16];
  const int* aff = (const int*)d_in[17];
  const int* eff = (const int*)d_in[18];

  // workspace layout (~30 MB; agg eliminated by the fusion)
  int* wsp        = (int*)d_ws;
  int* flags      = wsp;                    // [N]     (zeroed by k_prep b0)
  int* deg_c      = flags + kN;             // [kChunks*N]; becomes chunk_base in scan3
  int* row_off    = deg_c + kChunks * kN;   // [N+1] -> pad N+64
  int* partials   = row_off + (kN + 64);    // [512]
  int* dflag      = partials + 512;         // [16]
  float* projected = (float*)(dflag + 16);           // [128]
  float* eff_acc   = projected + 128;                // [8*128] (zeroed by prep b0)
  int* sorted_src  = (int*)(eff_acc + 1024);         // [E]
  unsigned int* pk  = (unsigned int*)(sorted_src + kE);  // [N*H]
  unsigned short* wt = (unsigned short*)(pk + kNH);      // [20480] bf16

  k_prep<<<1 + kHistB + kWprepBlocks, 1024, 0, stream>>>(
      (const unsigned short*)W_cand, obs, W_in, b_in, aff, dst,
      W_msg, W_gate, W_cand, dflag, flags, projected, deg_c, wt, eff_acc);
  k_scan1<<<kScanB, 256, 0, stream>>>(deg_c, row_off, partials);
  k_scan3<<<kScanB, 256, 0, stream>>>(row_off, partials, deg_c);
  k_scatter<<<kHistB + kPackBlocks, 1024, 0, stream>>>(
      src, dst, deg_c, sorted_src, (const unsigned short*)W_cand, state, pk);
  k_gupd<<<kGuB, 256, 0, stream>>>(pk, row_off, sorted_src, wt, b_gate, b_cand,
                                   flags, projected, dflag, d_out, eff, eff_acc);
  k_readout<<<1, 128, 0, stream>>>(W_dec, b_dec, W_mean, b_mean, W_ls, b_ls,
                                   eff_acc, dflag, d_out);
}

// Round 17
// 246.919 us; speedup vs baseline: 1.0981x; 1.0050x over previous
//
#include <hip/hip_runtime.h>
#include <hip/hip_bf16.h>

// Problem constants (WholeBrainRateModel)
constexpr int kN   = 50000;    // nodes
constexpr int kH   = 64;       // hidden
constexpr int kB   = 2;        // batch
constexpr int kE   = 1000000;  // edges
constexpr int kObs = 128;
constexpr int kA   = 18;
constexpr int kAff = 512;
constexpr int kEff = 256;
constexpr int kNH  = kN * kH;
constexpr int kOutOff = 2 * kB * kA;  // 72 elements: mean+log_std before next_state
constexpr int kRanges = 8;                // node ranges (bid&7 -> XCD heuristic)
constexpr int kNr  = kN / kRanges;        // 6250 nodes per range (25 KB LDS)
constexpr int kChunks = 32;               // edge chunks (round 17: 64->32 halves
                                          // deg_c scan traffic; 256 hist blocks
                                          // x 1024 thr still saturate)
constexpr int kEc  = kE / kChunks;        // 31250 edges per chunk
constexpr int kHistB = kRanges * kChunks; // 256 hist/scatter blocks (1024 thr)
constexpr int kPackPerR = (kNr + 127) / 128;      // 49 pack blocks per range
constexpr int kPackBlocks = kRanges * kPackPerR;  // 392 (range-aligned)
constexpr int kWprepBlocks = 20;                  // 20480 / 1024
constexpr int kScanB = (kN + 255) / 256;          // 196 (1 node/thread)
constexpr int kGuPerR = (kNr + 7) / 8;            // 782 fused blocks per range
constexpr int kGuB = kRanges * kGuPerR;           // 6256 (8 nodes/block)

typedef __attribute__((ext_vector_type(8))) short short8_t;  // 8 bf16 (4 VGPRs)
typedef __attribute__((ext_vector_type(4))) float f32x4_t;

// dtype-adaptive load/store (flag==1 -> float32 buffers, else bf16).
__device__ __forceinline__ float ldf(const void* p, int i, int f32) {
  if (f32) return ((const float*)p)[i];
  unsigned short u = ((const unsigned short*)p)[i];
  union { unsigned int x; float f; } v; v.x = ((unsigned int)u) << 16; return v.f;
}
__device__ __forceinline__ void stf(void* p, int i, float val, int f32) {
  if (f32) ((float*)p)[i] = val;
  else ((__hip_bfloat16*)p)[i] = __float2bfloat16(val);
}
__device__ __forceinline__ float lo16(unsigned int w) {
  union { unsigned int i; float f; } v; v.i = w << 16; return v.f;
}
__device__ __forceinline__ float hi16(unsigned int w) {
  union { unsigned int i; float f; } v; v.i = w & 0xffff0000u; return v.f;
}
__device__ __forceinline__ float b2f(unsigned short u) {
  union { unsigned int i; float f; } v; v.i = ((unsigned int)u) << 16; return v.f;
}
__device__ __forceinline__ unsigned int f2b(float f) {  // rne bf16 bits
  union { float f; unsigned int u; } v; v.f = f;
  unsigned int r = v.u + 0x7fffu + ((v.u >> 16) & 1u);
  return r >> 16;
}
// fast transcendentals: v_exp_f32 + v_rcp_f32; error ~1e-6 rel, far below the
// bf16 rounding already present in the pipeline (absmax budget ~2e-3).
__device__ __forceinline__ float fsig(float x) {
  return __builtin_amdgcn_rcpf(1.f + __expf(-x));
}
__device__ __forceinline__ float ftanh(float x) {
  return 1.f - 2.f * __builtin_amdgcn_rcpf(__expf(2.f * x) + 1.f);
}
// wave-0 dtype detector (identical data in every block -> identical answer)
__device__ __forceinline__ int detect64(const unsigned short* wprobe, int t) {
  int hits = 0;
  for (int k = 0; k < 4; ++k) {
    unsigned short u = wprobe[(t * 4 + k) * 2];
    int e = (u >> 7) & 0xFF;
    if ((u & 0x7FFFu) != 0 && e >= 108 && e <= 128) hits++;
  }
  for (int off = 32; off; off >>= 1) hits += __shfl_down(hits, off);
  return (hits < 128) ? 1 : 0;  // few plausible-bf16 => f32
}

// --- fused prep (1024 thr): b0 = detect+flags+proj; b1..256 = hist; wprep ---
// Histogram with ZERO global atomics (rounds 3/4: every global atomic costs a
// ~32 B EA write packet; 1M of them = ~32 MB + 45+ us). Round 5 lesson: keep
// high wave counts and short per-thread loops. Block (r,c) LDS-counts chunk
// c's edges landing in range r, then plain coalesced stores to deg_c[c][r].
extern "C" __global__ __launch_bounds__(1024) void k_prep(
    const unsigned short* __restrict__ wprobe,
    const void* __restrict__ obs,
    const void* __restrict__ W_in,
    const void* __restrict__ b_in,
    const int* __restrict__ aff_idx,
    const int* __restrict__ dst,
    const void* __restrict__ W_msg,
    const void* __restrict__ W_gate,
    const void* __restrict__ W_cand,
    int* __restrict__ dflag,
    int* __restrict__ flags,
    float* __restrict__ projected,
    int* __restrict__ deg_c,
    unsigned short* __restrict__ wt,
    float* __restrict__ eff_acc) {
  __shared__ int sdeg[kNr];
  int t = threadIdx.x, b = blockIdx.x;
  if (b == 0) {
    __shared__ int sflag;
    if (t < 64) { int f = detect64(wprobe, t); if (t == 0) { sflag = f; dflag[0] = f; } }
    for (int i = t; i < kN; i += 1024) flags[i] = 0;
    eff_acc[t] = 0.f;                      // 8 range slices x 128
    __syncthreads();
    int f32 = sflag;
    if (t < kAff) flags[aff_idx[t]] = 1;
    if (t < kB * kH) {
      int bb = t >> 6, h = t & 63;
      float acc = ldf(b_in, h, f32);
      for (int o = 0; o < kObs; ++o)
        acc += ldf(obs, bb * kObs + o, f32) * ldf(W_in, o * kH + h, f32);
      projected[t] = acc;
    }
  } else if (b <= kHistB) {
    int h = b - 1, r = h & 7, c = h >> 3;
    int r0 = r * kNr;
    for (int i = t; i < kNr; i += 1024) sdeg[i] = 0;
    __syncthreads();
    int end = (c + 1) * kEc;
    for (int e = c * kEc + t; e < end; e += 1024) {
      unsigned rel = (unsigned)(dst[e] - r0);
      if (rel < (unsigned)kNr) atomicAdd(&sdeg[rel], 1);  // LDS atomic only
    }
    __syncthreads();
    for (int i = t; i < kNr; i += 1024) deg_c[c * kN + r0 + i] = sdeg[i];
  } else {
    __shared__ int sflag;
    if (t < 64) { int f = detect64(wprobe, t); if (t == 0) sflag = f; }
    __syncthreads();
    int f32 = sflag;
    int i = (b - 1 - kHistB) * 1024 + t;  // 0..20479
    if (i < 4096) {
      int n = i >> 6, k = i & 63;
      wt[i] = (unsigned short)f2b(ldf(W_msg, k * 64 + n, f32));
    } else if (i < 12288) {
      int j = i - 4096; int n = j >> 7, k = j & 127;
      wt[i] = (unsigned short)f2b(ldf(W_gate, k * 64 + n, f32));
    } else if (i < 20480) {
      int j = i - 12288; int n = j >> 7, k = j & 127;
      wt[i] = (unsigned short)f2b(ldf(W_cand, k * 64 + n, f32));
    }
  }
}

// --- scan: 196 blocks x 256 thr, 1 node/thread ------------------------------
extern "C" __global__ void k_scan1(const int* __restrict__ deg_c,
                                   int* __restrict__ row_off,
                                   int* __restrict__ partials) {
  __shared__ int sd[256];
  int t = threadIdx.x;
  int n = blockIdx.x * 256 + t;
  int s = 0;
  if (n < kN) {
    for (int c = 0; c < kChunks; ++c) s += deg_c[c * kN + n];
  }
  sd[t] = s;
  __syncthreads();
  for (int off = 1; off < 256; off <<= 1) {
    int v = (t >= off) ? sd[t - off] : 0;
    __syncthreads();
    sd[t] += v;
    __syncthreads();
  }
  int excl = sd[t] - s;
  if (t == 255) partials[blockIdx.x] = sd[255];
  if (n < kN) row_off[n] = excl;
}

// scan2 folded in; additionally transforms deg_c in place into
// chunk_base[c][n] = row_off[n] + sum_{c'<c} deg_c[c'][n]  (atomic-free
// scatter positions). Each node column is owned by exactly one thread.
extern "C" __global__ void k_scan3(int* __restrict__ row_off,
                                   const int* __restrict__ partials,
                                   int* __restrict__ deg_c) {
  __shared__ int sd[256];
  int t = threadIdx.x;
  int s = 0;
  for (int j = t; j < (int)blockIdx.x; j += 256) s += partials[j];
  sd[t] = s;
  __syncthreads();
  for (int off = 128; off; off >>= 1) {
    if (t < off) sd[t] += sd[t + off];
    __syncthreads();
  }
  int base = sd[0];
  int n = blockIdx.x * 256 + t;
  if (n < kN) {
    int v = row_off[n] + base;
    row_off[n] = v;
    int run = v;
#pragma unroll 8
    for (int c = 0; c < kChunks; ++c) {
      int d = deg_c[c * kN + n];
      deg_c[c * kN + n] = run;   // in-place: deg -> chunk_base
      run += d;
    }
  }
  if (blockIdx.x == 0 && t == 0) row_off[kN] = kE;
}

// --- scatter (+pack riding along), 1024 thr: ZERO global atomics ------------
// Block (r,c): load range r's chunk_base slice into an LDS cursor, then for
// chunk c's in-range edges take slots via LDS atomicAdd and store. Slots are
// disjoint across chunks by construction (chunk_base prefix). bid&7 = r keeps
// each range's ~500 KB sorted_src window written by one XCD (L2 locality).
// Pack blocks (bid >= 256): range-aligned: pack block p handles nodes of
// range p&7 -> pk's range-r lines are written by XCD r's L2.
extern "C" __global__ __launch_bounds__(1024) void k_scatter(
    const int* __restrict__ src,
    const int* __restrict__ dst,
    const int* __restrict__ chunk_base,
    int* __restrict__ sorted_src,
    const unsigned short* __restrict__ wprobe,
    const void* __restrict__ state,
    unsigned int* __restrict__ pack) {
  __shared__ int scur[kNr];
  int t = threadIdx.x;
  if (blockIdx.x < kHistB) {
    int r = blockIdx.x & 7, c = blockIdx.x >> 3;
    int r0 = r * kNr;
    for (int i = t; i < kNr; i += 1024) scur[i] = chunk_base[c * kN + r0 + i];
    __syncthreads();
    int end = (c + 1) * kEc;
    for (int e = c * kEc + t; e < end; e += 1024) {
      unsigned rel = (unsigned)(dst[e] - r0);
      if (rel < (unsigned)kNr) {
        int pos = atomicAdd(&scur[rel], 1);   // LDS atomic only
        sorted_src[pos] = src[e];
      }
    }
  } else {
    __shared__ int sflag;
    if (t < 64) { int f = detect64(wprobe, t); if (t == 0) sflag = f; }
    __syncthreads();
    int f32 = sflag;
    int p = blockIdx.x - kHistB;           // kHistB = 256 (div by 8): XCD = p&7
    int x = p & 7, j = p >> 3;
    int nb = x * kNr + j * 128;            // first node of this pack block
    int nl = min(nb + 128, (x + 1) * kNr); // range-local node limit
    int i = nb * 64 + t * 8;               // 8 elems/thread
    if (i < nl * 64) {
      uint4 o0, o1;
      if (!f32) {
        // bf16 inputs: pack is a pure bit-interleave (no rounding round-trip)
        uint4 a = *(const uint4*)((const unsigned short*)state + i);
        uint4 c4 = *(const uint4*)((const unsigned short*)state + kNH + i);
        o0.x = (a.x & 0xffffu) | (c4.x << 16);
        o0.y = (a.x >> 16)     | (c4.x & 0xffff0000u);
        o0.z = (a.y & 0xffffu) | (c4.y << 16);
        o0.w = (a.y >> 16)     | (c4.y & 0xffff0000u);
        o1.x = (a.z & 0xffffu) | (c4.z << 16);
        o1.y = (a.z >> 16)     | (c4.z & 0xffff0000u);
        o1.z = (a.w & 0xffffu) | (c4.w << 16);
        o1.w = (a.w >> 16)     | (c4.w & 0xffff0000u);
      } else {
        const float* sf = (const float*)state;
        unsigned int w[8];
#pragma unroll
        for (int k = 0; k < 8; ++k)
          w[k] = f2b(sf[i + k]) | (f2b(sf[kNH + i + k]) << 16);
        o0 = make_uint4(w[0], w[1], w[2], w[3]);
        o1 = make_uint4(w[4], w[5], w[6], w[7]);
      }
      *(uint4*)&pack[i] = o0;
      *(uint4*)&pack[i + 4] = o1;
    }
  }
}

// --- FUSED gather+update v2: ALL 4 waves alive end-to-end -------------------
// Wave w gathers 2 nodes (high TLP) AND updates output cols [16w,16w+16).
// Hazards isolated via separate LDS areas: comb[16][68] bf16 (combined) and
// sres[16][64] f32 (results). 3 cheap 4-wave barriers. agg buffer eliminated.
// Round-16 measured: occupancy 72%, 2.2 TB/s effective on 137 MB compulsory
// random fetches — the gather floor is random-access BW, not occupancy.
extern "C" __global__ __launch_bounds__(256) void k_gupd(
    const unsigned int* __restrict__ pack,
    const int* __restrict__ row_off,     // span = [off[n], off[n+1])
    const int* __restrict__ sorted_src,
    const unsigned short* __restrict__ wt,   // prepped bf16 Wt msg|gate|cand
    const void* __restrict__ b_gate,
    const void* __restrict__ b_cand,
    const int* __restrict__ flags,
    const float* __restrict__ projected,
    const int* __restrict__ dflag,
    void* __restrict__ out,
    const int* __restrict__ eff_idx,
    float* __restrict__ eff_acc) {
  __shared__ uint4 lx4[274];           // 4384 B: strip [16 rows][136 u16]
  __shared__ unsigned short comb[16 * 68];  // 2176 B: combined bf16 [16][68]
  __shared__ float sres[16 * 64];      // 4096 B: results f32 [16][64]
  __shared__ int smatch[256];
  __shared__ int smcnt;
  unsigned short* lx = (unsigned short*)lx4;
  int t = threadIdx.x;
  int w = t >> 6, lane = t & 63;
  int g = lane >> 4, col = lane & 15;
  int x = blockIdx.x & 7, jb = blockIdx.x >> 3;
  int nd0 = x * kNr + jb * 8;    // block's first node (8 nodes)
  int rend = (x + 1) * kNr;      // range-local node limit
  if (nd0 >= rend) return;
  if (t == 0) smcnt = 0;

  const uint4* pk4 = (const uint4*)pack;

  // --- phase 1 (all 4 waves): stage state + gather own 2 nodes into strip ---
  if (lane < 32) {
    int ndl = 2 * w + (lane >> 4), c4 = lane & 15;
    int ndg = min(nd0 + ndl, rend - 1);
    uint4 pv = pk4[ndg * 16 + c4];
    int r0 = 2 * ndl;
    *(uint2*)&lx[r0 * 136 + c4 * 4] =
        make_uint2((pv.x & 0xffffu) | (pv.y << 16), (pv.z & 0xffffu) | (pv.w << 16));
    *(uint2*)&lx[(r0 + 1) * 136 + c4 * 4] =
        make_uint2((pv.x >> 16) | (pv.y & 0xffff0000u), (pv.z >> 16) | (pv.w & 0xffff0000u));
  }
#pragma unroll
  for (int sub = 0; sub < 2; ++sub) {
    int ndl = 2 * w + sub;
    int n = nd0 + ndl;
    if (n >= rend) break;
    int s = row_off[n], en = row_off[n + 1];
    float a0x = 0.f, a0y = 0.f, a0z = 0.f, a0w = 0.f;
    float a1x = 0.f, a1y = 0.f, a1z = 0.f, a1w = 0.f;
    for (int e = s; e < en; e += 8) {
#pragma unroll
      for (int h = 0; h < 2; ++h) {
        int ee = e + h * 4 + g;
        int idx = sorted_src[min(ee, en - 1)];
        uint4 wv = pk4[idx * 16 + col];
        if (ee >= en) { wv.x = 0u; wv.y = 0u; wv.z = 0u; wv.w = 0u; }
        a0x += lo16(wv.x); a1x += hi16(wv.x);
        a0y += lo16(wv.y); a1y += hi16(wv.y);
        a0z += lo16(wv.z); a1z += hi16(wv.z);
        a0w += lo16(wv.w); a1w += hi16(wv.w);
      }
    }
    a0x += __shfl_xor(a0x, 16); a0x += __shfl_xor(a0x, 32);
    a0y += __shfl_xor(a0y, 16); a0y += __shfl_xor(a0y, 32);
    a0z += __shfl_xor(a0z, 16); a0z += __shfl_xor(a0z, 32);
    a0w += __shfl_xor(a0w, 16); a0w += __shfl_xor(a0w, 32);
    a1x += __shfl_xor(a1x, 16); a1x += __shfl_xor(a1x, 32);
    a1y += __shfl_xor(a1y, 16); a1y += __shfl_xor(a1y, 32);
    a1z += __shfl_xor(a1z, 16); a1z += __shfl_xor(a1z, 32);
    a1w += __shfl_xor(a1w, 16); a1w += __shfl_xor(a1w, 32);
    if (g == 0) {
      int r0 = 2 * ndl;
      *(uint2*)&lx[r0 * 136 + 64 + col * 4] =
          make_uint2(f2b(a0x) | (f2b(a0y) << 16), f2b(a0z) | (f2b(a0w) << 16));
      *(uint2*)&lx[(r0 + 1) * 136 + 64 + col * 4] =
          make_uint2(f2b(a1x) | (f2b(a1y) << 16), f2b(a1z) | (f2b(a1w) << 16));
    }
  }
  __syncthreads();   // barrier A: strip (state + agg) complete

  // --- phase 2 (all 4 waves): msg MFMA for ct = w; combined -> comb ---
  int f32 = dflag[0];
  int q = g, l15 = col;
  const unsigned short* wm = wt;            // msg^T  [64][64]  (row = out col)
  const unsigned short* wg = wt + 4096;     // gate^T [64][128]
  const unsigned short* wc = wt + 12288;    // cand^T [64][128]

  short8_t a0 = *(const short8_t*)&lx[l15 * 136 + 64 + q * 8];
  short8_t a1 = *(const short8_t*)&lx[l15 * 136 + 96 + q * 8];
  f32x4_t macc = {0.f, 0.f, 0.f, 0.f};
  {
    short8_t b0 = *(const short8_t*)&wm[(w * 16 + l15) * 64 + q * 8];
    short8_t b1 = *(const short8_t*)&wm[(w * 16 + l15) * 64 + 32 + q * 8];
    macc = __builtin_amdgcn_mfma_f32_16x16x32_bf16(a0, b0, macc, 0, 0, 0);
    macc = __builtin_amdgcn_mfma_f32_16x16x32_bf16(a1, b1, macc, 0, 0, 0);
  }
  int nA = nd0 + q * 2, nB = nA + 1;
  int flA = (nA < rend) ? flags[nA] : 0;
  int flB = (nB < rend) ? flags[nB] : 0;
  {
    int c2 = w * 16 + l15;
    float pj0 = projected[c2], pj1 = projected[64 + c2];
#pragma unroll
    for (int r = 0; r < 4; ++r) {
      int row = q * 4 + r;
      int fl = (r < 2) ? flA : flB;
      float inj = fl ? ((row & 1) ? pj1 : pj0) : 0.f;
      comb[row * 68 + c2] = (unsigned short)f2b(macc[r] + inj);
    }
  }
  __syncthreads();   // barrier B: comb complete

  // --- phase 3 (all 4 waves): gate/cand for ct = w -> sres ---
  short8_t xa[4];
#pragma unroll
  for (int ks = 0; ks < 2; ++ks)      // K 0..63 from state (strip cols 0-63)
    xa[ks] = *(const short8_t*)&lx[l15 * 136 + ks * 32 + q * 8];
#pragma unroll
  for (int ks = 0; ks < 2; ++ks)      // K 64..127 from comb
    xa[2 + ks] = *(const short8_t*)&comb[l15 * 68 + ks * 32 + q * 8];
  // prev-state for own col block (strip cols untouched -> safe to read here)
  float ps[4];
#pragma unroll
  for (int rp = 0; rp < 2; ++rp) {
    int row = q * 4 + 2 * rp;
    ps[rp * 2 + 0] = b2f(lx[row * 136 + w * 16 + l15]);
    ps[rp * 2 + 1] = b2f(lx[(row + 1) * 136 + w * 16 + l15]);
  }
  {
    f32x4_t accg = {0.f, 0.f, 0.f, 0.f}, accc = {0.f, 0.f, 0.f, 0.f};
#pragma unroll
    for (int ks = 0; ks < 4; ++ks) {
      short8_t bg = *(const short8_t*)&wg[(w * 16 + l15) * 128 + ks * 32 + q * 8];
      short8_t bc = *(const short8_t*)&wc[(w * 16 + l15) * 128 + ks * 32 + q * 8];
      accg = __builtin_amdgcn_mfma_f32_16x16x32_bf16(xa[ks], bg, accg, 0, 0, 0);
      accc = __builtin_amdgcn_mfma_f32_16x16x32_bf16(xa[ks], bc, accc, 0, 0, 0);
    }
    int c2 = w * 16 + l15;
    float bgv = ldf(b_gate, c2, f32), bcv = ldf(b_cand, c2, f32);
#pragma unroll
    for (int rp = 0; rp < 2; ++rp) {
      int r = q * 4 + 2 * rp;   // strip row (batch0); r+1 = batch1
      float z0 = fsig(accg[2 * rp] + bgv);
      float c0 = ftanh(accc[2 * rp] + bcv);
      sres[r * 64 + c2] = (1.f - z0) * ps[rp * 2 + 0] + z0 * c0;
      float z1 = fsig(accg[2 * rp + 1] + bgv);
      float c1 = ftanh(accc[2 * rp + 1] + bcv);
      sres[(r + 1) * 64 + c2] = (1.f - z1) * ps[rp * 2 + 1] + z1 * c1;
    }
  }
  // eff-membership scan (1 entry/thread, L2-hot) before the last barrier
  int nlim = min(8, rend - nd0);
  if (t < kEff) {
    unsigned rel = (unsigned)(eff_idx[t] - nd0);
    if (rel < (unsigned)nlim) { int s = atomicAdd(&smcnt, 1); smatch[s] = (int)rel; }
  }
  __syncthreads();   // barrier C: sres + smatch complete

  // --- phase 4 (all 4 waves): block-linear aligned copy-out + eff tail ---
  int nvalid = nlim * 64;
  if (f32) {
    float* po = (float*)out + kOutOff;
#pragma unroll
    for (int p = 0; p < 2; ++p)
      for (int j = t * 4; j < nvalid; j += 1024) {
        int ndl = j >> 6, c = j & 63;
        float4 v = *(float4*)&sres[(ndl * 2 + p) * 64 + c];
        *(float4*)(po + p * kNH + nd0 * 64 + j) = v;
      }
  } else {
    unsigned short* po = (unsigned short*)out + kOutOff;
#pragma unroll
    for (int p = 0; p < 2; ++p)
      for (int j = t * 8; j < nvalid; j += 2048) {
        int ndl = j >> 6, c = j & 63;
        const float* base = &sres[(ndl * 2 + p) * 64 + c];
        float4 v0 = *(const float4*)base;
        float4 v1 = *(const float4*)(base + 4);
        uint4 o;
        o.x = f2b(v0.x) | (f2b(v0.y) << 16);
        o.y = f2b(v0.z) | (f2b(v0.w) << 16);
        o.z = f2b(v1.x) | (f2b(v1.y) << 16);
        o.w = f2b(v1.z) | (f2b(v1.w) << 16);
        *(uint4*)(po + p * kNH + nd0 * 64 + j) = o;
      }
  }

  // eff accumulation: t<128 handles (p,c); per-range slice (contention /8)
  int cnt = smcnt;
  if (cnt && t < 128) {
    int p = t >> 6, c = t & 63;
    float s = 0.f;
    for (int m = 0; m < cnt; ++m) {
      int rel = smatch[m];
      float v = sres[(rel * 2 + p) * 64 + c];
      if (!f32) v = b2f((unsigned short)f2b(v));   // match stored precision
      s += v;
    }
    atomicAdd(&eff_acc[x * 128 + p * 64 + c], s);  // device-scope, no fence
  }
}

// --- readout: tiny decode + policy heads from per-range eff_acc slices ------
// Kernel boundary provides cross-XCD visibility of k_gupd's eff_acc atomics
// (one command-processor flush instead of per-block fences — round 10).
extern "C" __global__ void k_readout(const void* __restrict__ W_dec,
                                     const void* __restrict__ b_dec,
                                     const void* __restrict__ W_mean,
                                     const void* __restrict__ b_mean,
                                     const void* __restrict__ W_ls,
                                     const void* __restrict__ b_ls,
                                     const float* __restrict__ eff_acc,
                                     const int* __restrict__ dflag,
                                     void* __restrict__ out) {
  __shared__ float ro[128], dec[128];
  int f32 = dflag[0];
  int t = threadIdx.x;            // 128 threads
  if (t < 128) {
    float s = 0.f;
#pragma unroll
    for (int r = 0; r < kRanges; ++r) s += eff_acc[r * 128 + t];
    ro[t] = s * (1.f / kEff);
  }
  __syncthreads();
  if (t < 128) {
    int bb = t >> 6, h = t & 63;
    float d = ldf(b_dec, h, f32);
    for (int k = 0; k < 64; ++k) d += ro[bb * 64 + k] * ldf(W_dec, k * 64 + h, f32);
    dec[t] = tanhf(d);
  }
  __syncthreads();
  if (t < kB * kA) {
    int bb = t / kA, a = t % kA;
    float m = ldf(b_mean, a, f32), l = ldf(b_ls, a, f32);
    for (int k = 0; k < 64; ++k) {
      float dv = dec[bb * 64 + k];
      m += dv * ldf(W_mean, k * kA + a, f32);
      l += dv * ldf(W_ls, k * kA + a, f32);
    }
    l = fminf(fmaxf(l, -5.f), 2.f);
    stf(out, t, m, f32);            // mean[2][18]
    stf(out, kB * kA + t, l, f32);  // log_std[2][18]
  }
}

extern "C" void kernel_launch(void* const* d_in, const int* in_sizes, int n_in,
                              void* d_out, int out_size, void* d_ws, size_t ws_size,
                              hipStream_t stream) {
  (void)in_sizes; (void)n_in; (void)out_size; (void)ws_size;
  const void* obs    = d_in[0];
  const void* state  = d_in[1];
  const void* W_in   = d_in[2];
  const void* b_in   = d_in[3];
  const void* W_msg  = d_in[4];
  const void* W_gate = d_in[5];
  const void* b_gate = d_in[6];
  const void* W_cand = d_in[7];
  const void* b_cand = d_in[8];
  const void* W_dec  = d_in[9];
  const void* b_dec  = d_in[10];
  const void* W_mean = d_in[11];
  const void* b_mean = d_in[12];
  const void* W_ls   = d_in[13];
  const void* b_ls   = d_in[14];
  const int* src = (const int*)d_in[15];
  const int* dst = (const int*)d_in[16];
  const int* aff = (const int*)d_in[17];
  const int* eff = (const int*)d_in[18];

  // workspace layout (~24 MB; agg eliminated, deg_c halved)
  int* wsp        = (int*)d_ws;
  int* flags      = wsp;                    // [N]     (zeroed by k_prep b0)
  int* deg_c      = flags + kN;             // [kChunks*N]; becomes chunk_base in scan3
  int* row_off    = deg_c + kChunks * kN;   // [N+1] -> pad N+64
  int* partials   = row_off + (kN + 64);    // [512]
  int* dflag      = partials + 512;         // [16]
  float* projected = (float*)(dflag + 16);           // [128]
  float* eff_acc   = projected + 128;                // [8*128] (zeroed by prep b0)
  int* sorted_src  = (int*)(eff_acc + 1024);         // [E]
  unsigned int* pk  = (unsigned int*)(sorted_src + kE);  // [N*H]
  unsigned short* wt = (unsigned short*)(pk + kNH);      // [20480] bf16

  k_prep<<<1 + kHistB + kWprepBlocks, 1024, 0, stream>>>(
      (const unsigned short*)W_cand, obs, W_in, b_in, aff, dst,
      W_msg, W_gate, W_cand, dflag, flags, projected, deg_c, wt, eff_acc);
  k_scan1<<<kScanB, 256, 0, stream>>>(deg_c, row_off, partials);
  k_scan3<<<kScanB, 256, 0, stream>>>(row_off, partials, deg_c);
  k_scatter<<<kHistB + kPackBlocks, 1024, 0, stream>>>(
      src, dst, deg_c, sorted_src, (const unsigned short*)W_cand, state, pk);
  k_gupd<<<kGuB, 256, 0, stream>>>(pk, row_off, sorted_src, wt, b_gate, b_cand,
                                   flags, projected, dflag, d_out, eff, eff_acc);
  k_readout<<<1, 128, 0, stream>>>(W_dec, b_dec, W_mean, b_mean, W_ls, b_ls,
                                   eff_acc, dflag, d_out);
}